// Round 1
// baseline (1464.209 us; speedup 1.0000x reference)
//
#include <hip/hip_runtime.h>
#include <hip/hip_bf16.h>
#include <math.h>

#define D 64
#define H 4
#define NB 4
#define HID 64
#define TILE 64
#define MAXDEG 256
#define NEG_SLOPE 0.2f

// ---------------- QKV: one block per node, 64 threads ----------------
__global__ void qkv_kernel(const float* __restrict__ emb,
                           const float* __restrict__ Qw, const float* __restrict__ Qb,
                           const float* __restrict__ Kw, const float* __restrict__ Kb,
                           const float* __restrict__ Vw, const float* __restrict__ Vb,
                           float* __restrict__ Q, float* __restrict__ K, float* __restrict__ V)
{
    __shared__ float e[D];
    const int n = blockIdx.x, d = threadIdx.x;
    e[d] = emb[n * D + d];
    __syncthreads();
    float aq = Qb[d], ak = Kb[d], av = Vb[d];
#pragma unroll 8
    for (int k = 0; k < D; ++k) {
        const float x = e[k];
        aq += x * Qw[k * D + d];
        ak += x * Kw[k * D + d];
        av += x * Vw[k * D + d];
    }
    Q[n * D + d] = aq;
    K[n * D + d] = ak;
    V[n * D + d] = av;
}

// ---------------- count edges per row (s_all) and per bond ----------------
__global__ void count_kernel(const int* __restrict__ src, const int* __restrict__ dst,
                             const int* __restrict__ bond, int Ep,
                             int* __restrict__ rowCnt, int* __restrict__ bondCnt)
{
    const int e = blockIdx.x * 256 + threadIdx.x;
    if (e >= 2 * Ep) return;
    const int s  = (e < Ep) ? src[e]  : dst[e - Ep];
    const int bt = (e < Ep) ? bond[e] : bond[e - Ep];
    atomicAdd(&rowCnt[s], 1);
    atomicAdd(&bondCnt[bt], 1);
}

// ---------------- exclusive scan of row counts (single block), N <= 4096 ----------------
__global__ void scan_kernel(const int* __restrict__ rowCnt, int* __restrict__ rowStart,
                            const int* __restrict__ bondCnt, int* __restrict__ bondOff, int N)
{
    __shared__ int part[1024];
    const int t = threadIdx.x;
    const int base = t * 4;
    int loc[4];
    int s = 0;
#pragma unroll
    for (int i = 0; i < 4; ++i) {
        const int idx = base + i;
        const int v = (idx < N) ? rowCnt[idx] : 0;
        loc[i] = s;
        s += v;
    }
    part[t] = s;
    __syncthreads();
    int val = s;
    for (int off = 1; off < 1024; off <<= 1) {
        const int other = (t >= off) ? part[t - off] : 0;
        __syncthreads();
        val += other;
        part[t] = val;
        __syncthreads();
    }
    const int excl = val - s;
#pragma unroll
    for (int i = 0; i < 4; ++i) {
        const int idx = base + i;
        if (idx < N) rowStart[idx] = excl + loc[i];
    }
    if (t == 1023) rowStart[N] = val;  // grand total
    if (t == 0) {
        int o = 0;
        for (int b = 0; b < NB; ++b) { bondOff[b] = o; o += bondCnt[b]; }
        bondOff[NB] = o;
    }
}

// ---------------- scatter edges into row-CSR and bond buckets ----------------
__global__ void scatter_kernel(const int* __restrict__ src, const int* __restrict__ dst,
                               const int* __restrict__ bond, int Ep,
                               const int* __restrict__ rowStart, int* __restrict__ rowFill,
                               const int* __restrict__ bondOff, int* __restrict__ bondFill,
                               int* __restrict__ edge_col, int* __restrict__ edge_eid,
                               int* __restrict__ bond_edges)
{
    const int e = blockIdx.x * 256 + threadIdx.x;
    if (e >= 2 * Ep) return;
    int s, d, bt;
    if (e < Ep) { s = src[e]; d = dst[e]; bt = bond[e]; }
    else        { s = dst[e - Ep]; d = src[e - Ep]; bt = bond[e - Ep]; }
    const int p = rowStart[s] + atomicAdd(&rowFill[s], 1);
    edge_col[p] = d;
    edge_eid[p] = e;
    const int q = bondOff[bt] + atomicAdd(&bondFill[bt], 1);
    bond_edges[q] = e;
}

// ---------------- grouped edge MLP: 64-edge tile per (bond, head) ----------------
// block = 256 threads: lane (tid&63) = edge within tile, group g (tid>>6) = 16-wide j slice.
__global__ __launch_bounds__(256) void mlp_kernel(
    const float* __restrict__ Q, const float* __restrict__ K,
    const int* __restrict__ src, const int* __restrict__ dst, int Ep,
    const int* __restrict__ bondOff, const int* __restrict__ bond_edges,
    const float* __restrict__ W0, const float* __restrict__ b0,
    const float* __restrict__ W1, const float* __restrict__ b1,
    const float* __restrict__ W2, const float* __restrict__ b2,
    float* __restrict__ scores)
{
    const int bt = blockIdx.y, h = blockIdx.z;
    const int base = bondOff[bt];
    const int cnt = bondOff[bt + 1] - base;
    const int t0 = blockIdx.x * TILE;
    if (t0 >= cnt) return;
    const int ne = min(TILE, cnt - t0);

    __shared__ float xs[TILE][129];   // stride 129: conflict-free scalar reads per-lane
    __shared__ float h0s[TILE][65];   // stride 65: conflict-free
    __shared__ int   eids[TILE];
    __shared__ float part[4][TILE];

    const int tid = threadIdx.x;
    if (tid < TILE) eids[tid] = (tid < ne) ? bond_edges[base + t0 + tid] : 0;
    __syncthreads();

    // gather x = [Q[s_all], K[d_all]]
    for (int i = tid; i < TILE * 128; i += 256) {
        const int el = i >> 7, k = i & 127;
        float v = 0.f;
        if (el < ne) {
            const int e = eids[el];
            int s, d;
            if (e < Ep) { s = src[e]; d = dst[e]; }
            else        { s = dst[e - Ep]; d = src[e - Ep]; }
            v = (k < 64) ? Q[s * D + k] : K[d * D + (k - 64)];
        }
        xs[el][k] = v;
    }
    __syncthreads();

    const int edge = tid & 63;
    const int g = tid >> 6;         // j = g*16 + jj
    const int bh = bt * H + h;

    // ---- layer 0: h0 = relu(x @ W0 + b0), K=128 ----
    const float* w0 = W0 + (size_t)bh * 128 * HID;
    const float* bb0 = b0 + bh * HID;
    float acc[16];
#pragma unroll
    for (int jj = 0; jj < 16; ++jj) acc[jj] = bb0[g * 16 + jj];
#pragma unroll 4
    for (int k = 0; k < 128; ++k) {
        const float xk = xs[edge][k];
        const float4 wa = *(const float4*)(w0 + (k << 6) + (g << 4));
        const float4 wb = *(const float4*)(w0 + (k << 6) + (g << 4) + 4);
        const float4 wc = *(const float4*)(w0 + (k << 6) + (g << 4) + 8);
        const float4 wd = *(const float4*)(w0 + (k << 6) + (g << 4) + 12);
        acc[0] += xk * wa.x; acc[1] += xk * wa.y; acc[2] += xk * wa.z; acc[3] += xk * wa.w;
        acc[4] += xk * wb.x; acc[5] += xk * wb.y; acc[6] += xk * wb.z; acc[7] += xk * wb.w;
        acc[8] += xk * wc.x; acc[9] += xk * wc.y; acc[10] += xk * wc.z; acc[11] += xk * wc.w;
        acc[12] += xk * wd.x; acc[13] += xk * wd.y; acc[14] += xk * wd.z; acc[15] += xk * wd.w;
    }
#pragma unroll
    for (int jj = 0; jj < 16; ++jj) h0s[edge][g * 16 + jj] = fmaxf(acc[jj], 0.f);
    __syncthreads();

    // ---- layer 1: h1 = relu(h0 @ W1 + b1), K=64 (h1 stays in registers) ----
    const float* w1 = W1 + (size_t)bh * HID * HID;
    const float* bb1 = b1 + bh * HID;
    float acc1[16];
#pragma unroll
    for (int jj = 0; jj < 16; ++jj) acc1[jj] = bb1[g * 16 + jj];
#pragma unroll 4
    for (int k = 0; k < HID; ++k) {
        const float xk = h0s[edge][k];
        const float4 wa = *(const float4*)(w1 + (k << 6) + (g << 4));
        const float4 wb = *(const float4*)(w1 + (k << 6) + (g << 4) + 4);
        const float4 wc = *(const float4*)(w1 + (k << 6) + (g << 4) + 8);
        const float4 wd = *(const float4*)(w1 + (k << 6) + (g << 4) + 12);
        acc1[0] += xk * wa.x; acc1[1] += xk * wa.y; acc1[2] += xk * wa.z; acc1[3] += xk * wa.w;
        acc1[4] += xk * wb.x; acc1[5] += xk * wb.y; acc1[6] += xk * wb.z; acc1[7] += xk * wb.w;
        acc1[8] += xk * wc.x; acc1[9] += xk * wc.y; acc1[10] += xk * wc.z; acc1[11] += xk * wc.w;
        acc1[12] += xk * wd.x; acc1[13] += xk * wd.y; acc1[14] += xk * wd.z; acc1[15] += xk * wd.w;
    }

    // ---- layer 2: sc = h1 . W2 + b2, then leaky_relu ----
    const float* w2 = W2 + bh * HID;
    float p = 0.f;
#pragma unroll
    for (int jj = 0; jj < 16; ++jj) {
        const float v = fmaxf(acc1[jj], 0.f);
        p += v * w2[g * 16 + jj];
    }
    part[g][edge] = p;
    __syncthreads();
    if (tid < TILE) {
        float sc = part[0][tid] + part[1][tid] + part[2][tid] + part[3][tid] + b2[bh];
        sc = sc > 0.f ? sc : NEG_SLOPE * sc;
        if (tid < ne) scores[(size_t)eids[tid] * H + h] = sc;
    }
}

// ---------------- softmax + V aggregation per row (dedup: last edge index wins) ----------------
__global__ void agg_kernel(const float* __restrict__ V, const float* __restrict__ scores,
                           const int* __restrict__ rowStart, const int* __restrict__ edge_col,
                           const int* __restrict__ edge_eid, float* __restrict__ out_attn)
{
    const int row = blockIdx.x;
    const int lane = threadIdx.x;   // 64
    const int beg = rowStart[row];
    int deg = rowStart[row + 1] - beg;
    if (deg > MAXDEG) deg = MAXDEG;

    __shared__ int tcol[MAXDEG], teid[MAXDEG];
    __shared__ int scol[MAXDEG], seid[MAXDEG];
    __shared__ int win[MAXDEG];
    __shared__ float wgt[MAXDEG];

    for (int a = lane; a < deg; a += 64) { tcol[a] = edge_col[beg + a]; teid[a] = edge_eid[beg + a]; }
    __syncthreads();
    // deterministic sort by (unique) global edge id via rank
    for (int a = lane; a < deg; a += 64) {
        const int e = teid[a];
        int r = 0;
        for (int b = 0; b < deg; ++b) r += (teid[b] < e);
        scol[r] = tcol[a];
        seid[r] = e;
    }
    __syncthreads();
    // winner = last occurrence of each column in edge-index order
    for (int a = lane; a < deg; a += 64) {
        const int c = scol[a];
        int wn = 1;
        for (int b = a + 1; b < deg; ++b) if (scol[b] == c) { wn = 0; break; }
        win[a] = wn;
    }
    __syncthreads();

    for (int h = 0; h < H; ++h) {
        float m = -1e30f;
        for (int a = lane; a < deg; a += 64)
            if (win[a]) m = fmaxf(m, scores[(size_t)seid[a] * H + h]);
#pragma unroll
        for (int off = 32; off; off >>= 1) m = fmaxf(m, __shfl_xor(m, off, 64));

        for (int a = lane; a < deg; a += 64)
            wgt[a] = win[a] ? __expf(scores[(size_t)seid[a] * H + h] - m) : 0.f;
        __syncthreads();

        float dn = 0.f;
        for (int a = lane; a < deg; a += 64) dn += wgt[a];
#pragma unroll
        for (int off = 32; off; off >>= 1) dn += __shfl_xor(dn, off, 64);

        float accv = 0.f;
        for (int a = 0; a < deg; ++a) {
            const float wv = wgt[a];
            if (wv != 0.f) accv += wv * V[(size_t)scol[a] * D + lane];
        }
        out_attn[(size_t)row * (H * D) + h * D + lane] = accv / dn;
        __syncthreads();
    }
}

// ---------------- final projection: [N,256] @ [256,64] + Pb ----------------
__global__ void proj_kernel(const float* __restrict__ out_attn, const float* __restrict__ Pw,
                            const float* __restrict__ Pb, float* __restrict__ out)
{
    __shared__ float r[H * D];
    const int n = blockIdx.x, d = threadIdx.x;  // 64 threads
    for (int i = d; i < H * D; i += D) r[i] = out_attn[(size_t)n * (H * D) + i];
    __syncthreads();
    float acc = Pb[d];
#pragma unroll 8
    for (int k = 0; k < H * D; ++k) acc += r[k] * Pw[k * D + d];
    out[(size_t)n * D + d] = acc;
}

extern "C" void kernel_launch(void* const* d_in, const int* in_sizes, int n_in,
                              void* d_out, int out_size, void* d_ws, size_t ws_size,
                              hipStream_t stream)
{
    const float* emb = (const float*)d_in[0];
    const float* Qw  = (const float*)d_in[1];
    const float* Qb  = (const float*)d_in[2];
    const float* Kw  = (const float*)d_in[3];
    const float* Kb  = (const float*)d_in[4];
    const float* Vw  = (const float*)d_in[5];
    const float* Vb  = (const float*)d_in[6];
    const float* W0  = (const float*)d_in[7];
    const float* b0  = (const float*)d_in[8];
    const float* W1  = (const float*)d_in[9];
    const float* b1  = (const float*)d_in[10];
    const float* W2  = (const float*)d_in[11];
    const float* b2  = (const float*)d_in[12];
    const float* Pw  = (const float*)d_in[13];
    const float* Pb  = (const float*)d_in[14];
    const int* src   = (const int*)d_in[15];
    const int* dst   = (const int*)d_in[16];
    const int* bond  = (const int*)d_in[17];

    const int N  = in_sizes[0] / D;
    const int Ep = in_sizes[15];
    const int TE = 2 * Ep;

    // ---- workspace layout ----
    char* w = (char*)d_ws;
    auto alloc = [&](size_t bytes) -> void* {
        void* p = (void*)w;
        w += ((bytes + 255) / 256) * 256;
        return p;
    };
    float* Q        = (float*)alloc((size_t)N * D * 4);
    float* Kx       = (float*)alloc((size_t)N * D * 4);
    float* V        = (float*)alloc((size_t)N * D * 4);
    float* scores   = (float*)alloc((size_t)TE * H * 4);
    float* out_attn = (float*)alloc((size_t)N * H * D * 4);
    int* rowStart   = (int*)alloc((size_t)(N + 1) * 4);
    int* bondOff    = (int*)alloc((size_t)(NB + 1) * 4);
    int* edge_col   = (int*)alloc((size_t)TE * 4);
    int* edge_eid   = (int*)alloc((size_t)TE * 4);
    int* bond_edges = (int*)alloc((size_t)TE * 4);
    int* counters   = (int*)alloc((size_t)(2 * N + 2 * NB) * 4);
    if ((size_t)(w - (char*)d_ws) > ws_size) return;  // insufficient workspace: fail loudly

    int* rowCnt   = counters;
    int* rowFill  = counters + N;
    int* bondCnt  = counters + 2 * N;
    int* bondFill = counters + 2 * N + NB;

    hipMemsetAsync(counters, 0, (size_t)(2 * N + 2 * NB) * 4, stream);

    qkv_kernel<<<N, D, 0, stream>>>(emb, Qw, Qb, Kw, Kb, Vw, Vb, Q, Kx, V);
    count_kernel<<<(TE + 255) / 256, 256, 0, stream>>>(src, dst, bond, Ep, rowCnt, bondCnt);
    scan_kernel<<<1, 1024, 0, stream>>>(rowCnt, rowStart, bondCnt, bondOff, N);
    scatter_kernel<<<(TE + 255) / 256, 256, 0, stream>>>(src, dst, bond, Ep, rowStart, rowFill,
                                                         bondOff, bondFill, edge_col, edge_eid,
                                                         bond_edges);
    dim3 mgrid((TE + TILE - 1) / TILE, NB, H);
    mlp_kernel<<<mgrid, 256, 0, stream>>>(Q, Kx, src, dst, Ep, bondOff, bond_edges,
                                          W0, b0, W1, b1, W2, b2, scores);
    agg_kernel<<<N, 64, 0, stream>>>(V, scores, rowStart, edge_col, edge_eid, out_attn);
    proj_kernel<<<N, D, 0, stream>>>(out_attn, Pw, Pb, (float*)d_out);
}

// Round 2
// 992.425 us; speedup vs baseline: 1.4754x; 1.4754x over previous
//
#include <hip/hip_runtime.h>
#include <hip/hip_bf16.h>
#include <math.h>

#define D 64
#define H 4
#define NB 4
#define HID 64
#define TILE 64
#define MAXDEG 256
#define NEG_SLOPE 0.2f

typedef __attribute__((ext_vector_type(8))) short short8;
typedef __attribute__((ext_vector_type(4))) float f32x4;

__device__ __forceinline__ unsigned short f2bf(float f) {
    union { float f; unsigned int u; } c; c.f = f;
    const unsigned int u = c.u;
    return (unsigned short)((u + 0x7fffu + ((u >> 16) & 1u)) >> 16);
}

// ---------------- QKV: one block per node, 64 threads; Q,K as bf16, V fp32 ----------------
__global__ void qkv_kernel(const float* __restrict__ emb,
                           const float* __restrict__ Qw, const float* __restrict__ Qb,
                           const float* __restrict__ Kw, const float* __restrict__ Kb,
                           const float* __restrict__ Vw, const float* __restrict__ Vb,
                           unsigned short* __restrict__ Qbf, unsigned short* __restrict__ Kbf,
                           float* __restrict__ V)
{
    __shared__ float e[D];
    const int n = blockIdx.x, d = threadIdx.x;
    e[d] = emb[n * D + d];
    __syncthreads();
    float aq = Qb[d], ak = Kb[d], av = Vb[d];
#pragma unroll 8
    for (int k = 0; k < D; ++k) {
        const float x = e[k];
        aq += x * Qw[k * D + d];
        ak += x * Kw[k * D + d];
        av += x * Vw[k * D + d];
    }
    Qbf[n * D + d] = f2bf(aq);
    Kbf[n * D + d] = f2bf(ak);
    V[n * D + d] = av;
}

// ---------------- prepack weights into MFMA B-fragment order (bf16) ----------------
// W0p idx = ((((bh*4+ks)*4+nt)*64)+lane)*8 + j ; k = ks*32+(lane>>4)*8+j ; n = nt*16+(lane&15)
__global__ void prepack_kernel(const float* __restrict__ W0, const float* __restrict__ W1,
                               unsigned short* __restrict__ W0p, unsigned short* __restrict__ W1p)
{
    const int idx = blockIdx.x * 256 + threadIdx.x;
    if (idx < 131072) {
        const int j = idx & 7, lane = (idx >> 3) & 63, nt = (idx >> 9) & 3;
        const int ks = (idx >> 11) & 3, bh = idx >> 13;
        const int k = ks * 32 + ((lane >> 4) << 3) + j;
        const int n = (nt << 4) + (lane & 15);
        W0p[idx] = f2bf(W0[((size_t)bh * 128 + k) * 64 + n]);
    }
    if (idx < 65536) {
        const int j = idx & 7, lane = (idx >> 3) & 63, nt = (idx >> 9) & 3;
        const int ks = (idx >> 11) & 1, bh = idx >> 12;
        const int k = ks * 32 + ((lane >> 4) << 3) + j;
        const int n = (nt << 4) + (lane & 15);
        W1p[idx] = f2bf(W1[((size_t)bh * 64 + k) * 64 + n]);
    }
}

// ---------------- count edges per row (s_all) and per bond ----------------
__global__ void count_kernel(const int* __restrict__ src, const int* __restrict__ dst,
                             const int* __restrict__ bond, int Ep,
                             int* __restrict__ rowCnt, int* __restrict__ bondCnt)
{
    const int e = blockIdx.x * 256 + threadIdx.x;
    if (e >= 2 * Ep) return;
    const int s  = (e < Ep) ? src[e]  : dst[e - Ep];
    const int bt = (e < Ep) ? bond[e] : bond[e - Ep];
    atomicAdd(&rowCnt[s], 1);
    atomicAdd(&bondCnt[bt], 1);
}

// ---------------- exclusive scan of row counts (single block), N <= 4096 ----------------
__global__ void scan_kernel(const int* __restrict__ rowCnt, int* __restrict__ rowStart,
                            const int* __restrict__ bondCnt, int* __restrict__ bondOff, int N)
{
    __shared__ int part[1024];
    const int t = threadIdx.x;
    const int base = t * 4;
    int loc[4];
    int s = 0;
#pragma unroll
    for (int i = 0; i < 4; ++i) {
        const int idx = base + i;
        const int v = (idx < N) ? rowCnt[idx] : 0;
        loc[i] = s;
        s += v;
    }
    part[t] = s;
    __syncthreads();
    int val = s;
    for (int off = 1; off < 1024; off <<= 1) {
        const int other = (t >= off) ? part[t - off] : 0;
        __syncthreads();
        val += other;
        part[t] = val;
        __syncthreads();
    }
    const int excl = val - s;
#pragma unroll
    for (int i = 0; i < 4; ++i) {
        const int idx = base + i;
        if (idx < N) rowStart[idx] = excl + loc[i];
    }
    if (t == 1023) rowStart[N] = val;
    if (t == 0) {
        int o = 0;
        for (int b = 0; b < NB; ++b) { bondOff[b] = o; o += bondCnt[b]; }
        bondOff[NB] = o;
    }
}

// ---------------- scatter edges into row-CSR and bond buckets ----------------
__global__ void scatter_kernel(const int* __restrict__ src, const int* __restrict__ dst,
                               const int* __restrict__ bond, int Ep,
                               const int* __restrict__ rowStart, int* __restrict__ rowFill,
                               const int* __restrict__ bondOff, int* __restrict__ bondFill,
                               int* __restrict__ edge_col, int* __restrict__ edge_eid,
                               int* __restrict__ bond_edges)
{
    const int e = blockIdx.x * 256 + threadIdx.x;
    if (e >= 2 * Ep) return;
    int s, d, bt;
    if (e < Ep) { s = src[e]; d = dst[e]; bt = bond[e]; }
    else        { s = dst[e - Ep]; d = src[e - Ep]; bt = bond[e - Ep]; }
    const int p = rowStart[s] + atomicAdd(&rowFill[s], 1);
    edge_col[p] = d;
    edge_eid[p] = e;
    const int q = bondOff[bt] + atomicAdd(&bondFill[bt], 1);
    bond_edges[q] = e;
}

// ---------------- MFMA grouped edge MLP: 64-edge tile per bond, 4 waves = 4 heads ----------------
__global__ __launch_bounds__(256) void mlp_kernel(
    const unsigned short* __restrict__ Qbf, const unsigned short* __restrict__ Kbf,
    const int* __restrict__ src, const int* __restrict__ dst, int Ep,
    const int* __restrict__ bondOff, const int* __restrict__ bond_edges,
    const unsigned short* __restrict__ W0p, const unsigned short* __restrict__ W1p,
    const float* __restrict__ b0, const float* __restrict__ b1,
    const float* __restrict__ W2, const float* __restrict__ b2,
    float* __restrict__ scores)
{
    const int bt = blockIdx.y;
    const int base = bondOff[bt];
    const int cnt  = bondOff[bt + 1] - base;
    const int t0 = blockIdx.x * TILE;
    if (t0 >= cnt) return;
    const int ne = min(TILE, cnt - t0);

    __shared__ __align__(16) unsigned char xs[64 * 256];      // 64 edges x 128 bf16, XOR-swizzled
    __shared__ __align__(16) unsigned char h0s[4][64 * 128];  // per-wave H0: 64x64 bf16, swizzled
    __shared__ int eids[TILE];

    const int tid = threadIdx.x;
    if (tid < TILE) eids[tid] = (tid < ne) ? bond_edges[base + t0 + tid] : 0;
    __syncthreads();

    // gather x = [Q[s] | K[d]] as bf16 into swizzled LDS (16B units)
    for (int i = tid; i < 1024; i += 256) {
        const int el = i >> 4, u = i & 15;
        uint4 v = make_uint4(0, 0, 0, 0);
        if (el < ne) {
            const int e = eids[el];
            int s, d;
            if (e < Ep) { s = src[e]; d = dst[e]; }
            else        { s = dst[e - Ep]; d = src[e - Ep]; }
            v = (u < 8) ? ((const uint4*)(Qbf + s * 64))[u]
                        : ((const uint4*)(Kbf + d * 64))[u - 8];
        }
        const int b = (el << 8) + (u << 4);
        *(uint4*)(xs + (b ^ ((el & 7) << 4))) = v;
    }
    __syncthreads();

    const int lane = tid & 63;
    const int h = tid >> 6;          // wave = head
    const int bh = bt * H + h;
    const int lg = lane >> 4;        // 0..3
    const int lr = lane & 15;        // 0..15

    // ---- layer 0: H0 = relu(X @ W0 + b0), K=128 ----
    f32x4 acc[4][4];
    const float* bb0 = b0 + bh * HID;
#pragma unroll
    for (int nt = 0; nt < 4; ++nt) {
        const float bv = bb0[(nt << 4) + lr];
#pragma unroll
        for (int mt = 0; mt < 4; ++mt) acc[mt][nt] = (f32x4){bv, bv, bv, bv};
    }
    const short8* W0f = (const short8*)W0p + (size_t)bh * 1024;
#pragma unroll
    for (int ks = 0; ks < 4; ++ks) {
        short8 a[4];
        const int koff = (ks << 6) + (lg << 4);
#pragma unroll
        for (int mt = 0; mt < 4; ++mt) {
            const int row = (mt << 4) + lr;
            const int b = (row << 8) + koff;
            a[mt] = *(const short8*)(xs + (b ^ ((row & 7) << 4)));
        }
        short8 bfr[4];
#pragma unroll
        for (int nt = 0; nt < 4; ++nt) bfr[nt] = W0f[(((ks << 2) + nt) << 6) + lane];
#pragma unroll
        for (int mt = 0; mt < 4; ++mt)
#pragma unroll
            for (int nt = 0; nt < 4; ++nt)
                acc[mt][nt] = __builtin_amdgcn_mfma_f32_16x16x32_bf16(a[mt], bfr[nt], acc[mt][nt], 0, 0, 0);
    }
    // relu -> per-wave LDS (bf16, swizzled) for layer-1 A fragments
    unsigned char* h0 = h0s[h];
#pragma unroll
    for (int mt = 0; mt < 4; ++mt)
#pragma unroll
        for (int nt = 0; nt < 4; ++nt)
#pragma unroll
            for (int r = 0; r < 4; ++r) {
                const int row = (mt << 4) + (lg << 2) + r;
                const int col = (nt << 4) + lr;
                const int b = (row << 7) + (col << 1);
                *(unsigned short*)(h0 + (b ^ ((row & 7) << 4))) = f2bf(fmaxf(acc[mt][nt][r], 0.f));
            }

    // ---- layer 1: H1 = relu(H0 @ W1 + b1), K=64 ----
    f32x4 acc1[4][4];
    const float* bb1 = b1 + bh * HID;
#pragma unroll
    for (int nt = 0; nt < 4; ++nt) {
        const float bv = bb1[(nt << 4) + lr];
#pragma unroll
        for (int mt = 0; mt < 4; ++mt) acc1[mt][nt] = (f32x4){bv, bv, bv, bv};
    }
    const short8* W1f = (const short8*)W1p + (size_t)bh * 512;
#pragma unroll
    for (int ks = 0; ks < 2; ++ks) {
        short8 a[4];
        const int koff = (ks << 6) + (lg << 4);
#pragma unroll
        for (int mt = 0; mt < 4; ++mt) {
            const int row = (mt << 4) + lr;
            const int b = (row << 7) + koff;
            a[mt] = *(const short8*)(h0 + (b ^ ((row & 7) << 4)));
        }
        short8 bfr[4];
#pragma unroll
        for (int nt = 0; nt < 4; ++nt) bfr[nt] = W1f[(((ks << 2) + nt) << 6) + lane];
#pragma unroll
        for (int mt = 0; mt < 4; ++mt)
#pragma unroll
            for (int nt = 0; nt < 4; ++nt)
                acc1[mt][nt] = __builtin_amdgcn_mfma_f32_16x16x32_bf16(a[mt], bfr[nt], acc1[mt][nt], 0, 0, 0);
    }

    // ---- layer 2: sc = relu(H1) . w2 + b2, leaky-relu; in-register 16-lane reduce ----
    const float* w2 = W2 + bh * HID;
    float w2v[4];
#pragma unroll
    for (int nt = 0; nt < 4; ++nt) w2v[nt] = w2[(nt << 4) + lr];
    float p[4][4];
#pragma unroll
    for (int mt = 0; mt < 4; ++mt)
#pragma unroll
        for (int r = 0; r < 4; ++r) {
            float s = 0.f;
#pragma unroll
            for (int nt = 0; nt < 4; ++nt) s += fmaxf(acc1[mt][nt][r], 0.f) * w2v[nt];
            p[mt][r] = s;
        }
#pragma unroll
    for (int off = 1; off <= 8; off <<= 1)
#pragma unroll
        for (int mt = 0; mt < 4; ++mt)
#pragma unroll
            for (int r = 0; r < 4; ++r) p[mt][r] += __shfl_xor(p[mt][r], off, 64);
    // lane (lg,lr) writes edge = (lr>>2)*16 + lg*4 + (lr&3)
    const int e_w = ((lr >> 2) << 4) + (lg << 2) + (lr & 3);
    float sc = p[lr >> 2][lr & 3] + b2[bh];
    sc = sc > 0.f ? sc : NEG_SLOPE * sc;
    if (e_w < ne) scores[(size_t)eids[e_w] * H + h] = sc;
}

// ---------------- softmax + V aggregation: 256 threads, wave = head ----------------
__global__ __launch_bounds__(256) void agg_kernel(
    const float* __restrict__ V, const float* __restrict__ scores,
    const int* __restrict__ rowStart, const int* __restrict__ edge_col,
    const int* __restrict__ edge_eid, float* __restrict__ out_attn)
{
    const int row = blockIdx.x;
    const int tid = threadIdx.x;
    const int lane = tid & 63;
    const int h = tid >> 6;
    const int beg = rowStart[row];
    int deg = rowStart[row + 1] - beg;
    if (deg > MAXDEG) deg = MAXDEG;

    __shared__ int tcol[MAXDEG], teid[MAXDEG];
    __shared__ int scol[MAXDEG], seid[MAXDEG];
    __shared__ int win[MAXDEG];
    __shared__ float wgt[4][MAXDEG];

    for (int a = tid; a < deg; a += 256) { tcol[a] = edge_col[beg + a]; teid[a] = edge_eid[beg + a]; }
    __syncthreads();
    // deterministic sort by (unique) global edge id via rank
    for (int a = tid; a < deg; a += 256) {
        const int e = teid[a];
        int r = 0;
        for (int b = 0; b < deg; ++b) r += (teid[b] < e);
        scol[r] = tcol[a];
        seid[r] = e;
    }
    __syncthreads();
    // winner = last occurrence of each column in edge-index order
    for (int a = tid; a < deg; a += 256) {
        const int c = scol[a];
        int wn = 1;
        for (int b = a + 1; b < deg; ++b) if (scol[b] == c) { wn = 0; break; }
        win[a] = wn;
    }
    __syncthreads();

    float m = -1e30f;
    for (int a = lane; a < deg; a += 64)
        if (win[a]) m = fmaxf(m, scores[(size_t)seid[a] * H + h]);
#pragma unroll
    for (int off = 32; off; off >>= 1) m = fmaxf(m, __shfl_xor(m, off, 64));

    float dn = 0.f;
    for (int a = lane; a < deg; a += 64) {
        const float wv = win[a] ? __expf(scores[(size_t)seid[a] * H + h] - m) : 0.f;
        wgt[h][a] = wv;
        dn += wv;
    }
#pragma unroll
    for (int off = 32; off; off >>= 1) dn += __shfl_xor(dn, off, 64);

    float accv = 0.f;
    for (int a = 0; a < deg; ++a) {
        const float wv = wgt[h][a];
        if (wv != 0.f) accv += wv * V[(size_t)scol[a] * D + lane];
    }
    out_attn[(size_t)row * (H * D) + h * D + lane] = accv / dn;
}

// ---------------- final projection: [N,256] @ [256,64] + Pb ----------------
__global__ void proj_kernel(const float* __restrict__ out_attn, const float* __restrict__ Pw,
                            const float* __restrict__ Pb, float* __restrict__ out)
{
    __shared__ float r[H * D];
    const int n = blockIdx.x, d = threadIdx.x;  // 64 threads
    for (int i = d; i < H * D; i += D) r[i] = out_attn[(size_t)n * (H * D) + i];
    __syncthreads();
    float acc = Pb[d];
#pragma unroll 8
    for (int k = 0; k < H * D; ++k) acc += r[k] * Pw[k * D + d];
    out[(size_t)n * D + d] = acc;
}

extern "C" void kernel_launch(void* const* d_in, const int* in_sizes, int n_in,
                              void* d_out, int out_size, void* d_ws, size_t ws_size,
                              hipStream_t stream)
{
    const float* emb = (const float*)d_in[0];
    const float* Qw  = (const float*)d_in[1];
    const float* Qb  = (const float*)d_in[2];
    const float* Kw  = (const float*)d_in[3];
    const float* Kb  = (const float*)d_in[4];
    const float* Vw  = (const float*)d_in[5];
    const float* Vb  = (const float*)d_in[6];
    const float* W0  = (const float*)d_in[7];
    const float* b0  = (const float*)d_in[8];
    const float* W1  = (const float*)d_in[9];
    const float* b1  = (const float*)d_in[10];
    const float* W2  = (const float*)d_in[11];
    const float* b2  = (const float*)d_in[12];
    const float* Pw  = (const float*)d_in[13];
    const float* Pb  = (const float*)d_in[14];
    const int* src   = (const int*)d_in[15];
    const int* dst   = (const int*)d_in[16];
    const int* bond  = (const int*)d_in[17];

    const int N  = in_sizes[0] / D;
    const int Ep = in_sizes[15];
    const int TE = 2 * Ep;

    // ---- workspace layout ----
    char* w = (char*)d_ws;
    auto alloc = [&](size_t bytes) -> void* {
        void* p = (void*)w;
        w += ((bytes + 255) / 256) * 256;
        return p;
    };
    unsigned short* Qbf = (unsigned short*)alloc((size_t)N * D * 2);
    unsigned short* Kbf = (unsigned short*)alloc((size_t)N * D * 2);
    float* V        = (float*)alloc((size_t)N * D * 4);
    unsigned short* W0p = (unsigned short*)alloc((size_t)131072 * 2);
    unsigned short* W1p = (unsigned short*)alloc((size_t)65536 * 2);
    float* scores   = (float*)alloc((size_t)TE * H * 4);
    float* out_attn = (float*)alloc((size_t)N * H * D * 4);
    int* rowStart   = (int*)alloc((size_t)(N + 1) * 4);
    int* bondOff    = (int*)alloc((size_t)(NB + 1) * 4);
    int* edge_col   = (int*)alloc((size_t)TE * 4);
    int* edge_eid   = (int*)alloc((size_t)TE * 4);
    int* bond_edges = (int*)alloc((size_t)TE * 4);
    int* counters   = (int*)alloc((size_t)(2 * N + 2 * NB) * 4);
    if ((size_t)(w - (char*)d_ws) > ws_size) return;

    int* rowCnt   = counters;
    int* rowFill  = counters + N;
    int* bondCnt  = counters + 2 * N;
    int* bondFill = counters + 2 * N + NB;

    hipMemsetAsync(counters, 0, (size_t)(2 * N + 2 * NB) * 4, stream);

    qkv_kernel<<<N, D, 0, stream>>>(emb, Qw, Qb, Kw, Kb, Vw, Vb, Qbf, Kbf, V);
    prepack_kernel<<<512, 256, 0, stream>>>(W0, W1, W0p, W1p);
    count_kernel<<<(TE + 255) / 256, 256, 0, stream>>>(src, dst, bond, Ep, rowCnt, bondCnt);
    scan_kernel<<<1, 1024, 0, stream>>>(rowCnt, rowStart, bondCnt, bondOff, N);
    scatter_kernel<<<(TE + 255) / 256, 256, 0, stream>>>(src, dst, bond, Ep, rowStart, rowFill,
                                                         bondOff, bondFill, edge_col, edge_eid,
                                                         bond_edges);
    dim3 mgrid((TE + TILE - 1) / TILE, NB);
    mlp_kernel<<<mgrid, 256, 0, stream>>>(Qbf, Kbf, src, dst, Ep, bondOff, bond_edges,
                                          W0p, W1p, b0, b1, W2, b2, scores);
    agg_kernel<<<N, 256, 0, stream>>>(V, scores, rowStart, edge_col, edge_eid, out_attn);
    proj_kernel<<<N, D, 0, stream>>>(out_attn, Pw, Pb, (float*)d_out);
}

// Round 3
// 198.174 us; speedup vs baseline: 7.3885x; 5.0078x over previous
//
#include <hip/hip_runtime.h>
#include <hip/hip_bf16.h>
#include <math.h>

#define D 64
#define H 4
#define NB 4
#define HID 64
#define TILE 64
#define MAXDEG 256
#define NEG_SLOPE 0.2f

typedef __attribute__((ext_vector_type(8))) short short8;
typedef __attribute__((ext_vector_type(4))) float f32x4;

__device__ __forceinline__ unsigned short f2bf(float f) {
    union { float f; unsigned int u; } c; c.f = f;
    const unsigned int u = c.u;
    return (unsigned short)((u + 0x7fffu + ((u >> 16) & 1u)) >> 16);
}

// ---------------- QKV: one block per node, 64 threads; Q,K as bf16, V fp32 ----------------
__global__ void qkv_kernel(const float* __restrict__ emb,
                           const float* __restrict__ Qw, const float* __restrict__ Qb,
                           const float* __restrict__ Kw, const float* __restrict__ Kb,
                           const float* __restrict__ Vw, const float* __restrict__ Vb,
                           unsigned short* __restrict__ Qbf, unsigned short* __restrict__ Kbf,
                           float* __restrict__ V)
{
    __shared__ float e[D];
    const int n = blockIdx.x, d = threadIdx.x;
    e[d] = emb[n * D + d];
    __syncthreads();
    float aq = Qb[d], ak = Kb[d], av = Vb[d];
#pragma unroll 8
    for (int k = 0; k < D; ++k) {
        const float x = e[k];
        aq += x * Qw[k * D + d];
        ak += x * Kw[k * D + d];
        av += x * Vw[k * D + d];
    }
    Qbf[n * D + d] = f2bf(aq);
    Kbf[n * D + d] = f2bf(ak);
    V[n * D + d] = av;
}

// ---------------- prepack weights into MFMA B-fragment order (bf16) ----------------
__global__ void prepack_kernel(const float* __restrict__ W0, const float* __restrict__ W1,
                               unsigned short* __restrict__ W0p, unsigned short* __restrict__ W1p)
{
    const int idx = blockIdx.x * 256 + threadIdx.x;
    if (idx < 131072) {
        const int j = idx & 7, lane = (idx >> 3) & 63, nt = (idx >> 9) & 3;
        const int ks = (idx >> 11) & 3, bh = idx >> 13;
        const int k = ks * 32 + ((lane >> 4) << 3) + j;
        const int n = (nt << 4) + (lane & 15);
        W0p[idx] = f2bf(W0[((size_t)bh * 128 + k) * 64 + n]);
    }
    if (idx < 65536) {
        const int j = idx & 7, lane = (idx >> 3) & 63, nt = (idx >> 9) & 3;
        const int ks = (idx >> 11) & 1, bh = idx >> 12;
        const int k = ks * 32 + ((lane >> 4) << 3) + j;
        const int n = (nt << 4) + (lane & 15);
        W1p[idx] = f2bf(W1[((size_t)bh * 64 + k) * 64 + n]);
    }
}

// ---------------- count edges per row (s_all) and per bond (wave-aggregated) ----------------
__global__ void count_kernel(const int* __restrict__ src, const int* __restrict__ dst,
                             const int* __restrict__ bond, int Ep,
                             int* __restrict__ rowCnt, int* __restrict__ bondCnt)
{
    const int e = blockIdx.x * 256 + threadIdx.x;
    const int lane = threadIdx.x & 63;
    const bool act = (e < 2 * Ep);
    int s = 0, bt = -1;
    if (act) {
        s  = (e < Ep) ? src[e]  : dst[e - Ep];
        bt = (e < Ep) ? bond[e] : bond[e - Ep];
        atomicAdd(&rowCnt[s], 1);
    }
#pragma unroll
    for (int t = 0; t < NB; ++t) {
        const unsigned long long mask = __ballot(bt == t);
        if (bt == t) {
            const int leader = __ffsll((long long)mask) - 1;
            if (lane == leader) atomicAdd(&bondCnt[t], (int)__popcll(mask));
        }
    }
}

// ---------------- exclusive scan of row counts (single block), N <= 4096 ----------------
__global__ void scan_kernel(const int* __restrict__ rowCnt, int* __restrict__ rowStart,
                            const int* __restrict__ bondCnt, int* __restrict__ bondOff, int N)
{
    __shared__ int part[1024];
    const int t = threadIdx.x;
    const int base = t * 4;
    int loc[4];
    int s = 0;
#pragma unroll
    for (int i = 0; i < 4; ++i) {
        const int idx = base + i;
        const int v = (idx < N) ? rowCnt[idx] : 0;
        loc[i] = s;
        s += v;
    }
    part[t] = s;
    __syncthreads();
    int val = s;
    for (int off = 1; off < 1024; off <<= 1) {
        const int other = (t >= off) ? part[t - off] : 0;
        __syncthreads();
        val += other;
        part[t] = val;
        __syncthreads();
    }
    const int excl = val - s;
#pragma unroll
    for (int i = 0; i < 4; ++i) {
        const int idx = base + i;
        if (idx < N) rowStart[idx] = excl + loc[i];
    }
    if (t == 1023) rowStart[N] = val;
    if (t == 0) {
        int o = 0;
        for (int b = 0; b < NB; ++b) { bondOff[b] = o; o += bondCnt[b]; }
        bondOff[NB] = o;
    }
}

// ---------------- scatter edges into row-CSR and bond buckets (wave-aggregated bond atomics) ----------------
__global__ void scatter_kernel(const int* __restrict__ src, const int* __restrict__ dst,
                               const int* __restrict__ bond, int Ep,
                               const int* __restrict__ rowStart, int* __restrict__ rowFill,
                               const int* __restrict__ bondOff, int* __restrict__ bondFill,
                               int* __restrict__ edge_col, int* __restrict__ edge_eid,
                               int* __restrict__ bond_edges)
{
    const int e = blockIdx.x * 256 + threadIdx.x;
    const int lane = threadIdx.x & 63;
    const bool act = (e < 2 * Ep);
    int s = 0, d = 0, bt = -1;
    if (act) {
        if (e < Ep) { s = src[e]; d = dst[e]; bt = bond[e]; }
        else        { s = dst[e - Ep]; d = src[e - Ep]; bt = bond[e - Ep]; }
        const int p = rowStart[s] + atomicAdd(&rowFill[s], 1);
        edge_col[p] = d;
        edge_eid[p] = e;
    }
    int q = -1;
#pragma unroll
    for (int t = 0; t < NB; ++t) {
        const unsigned long long mask = __ballot(bt == t);
        if (bt == t) {
            const int leader = __ffsll((long long)mask) - 1;
            const int rank = (int)__popcll(mask & ((1ull << lane) - 1ull));
            int b = 0;
            if (lane == leader) b = atomicAdd(&bondFill[t], (int)__popcll(mask));
            b = __shfl(b, leader, 64);
            q = bondOff[t] + b + rank;
        }
    }
    if (act) bond_edges[q] = e;
}

// ---------------- MFMA grouped edge MLP: 64-edge tile per bond, 4 waves = 4 heads ----------------
__global__ __launch_bounds__(256) void mlp_kernel(
    const unsigned short* __restrict__ Qbf, const unsigned short* __restrict__ Kbf,
    const int* __restrict__ src, const int* __restrict__ dst, int Ep,
    const int* __restrict__ bondOff, const int* __restrict__ bond_edges,
    const unsigned short* __restrict__ W0p, const unsigned short* __restrict__ W1p,
    const float* __restrict__ b0, const float* __restrict__ b1,
    const float* __restrict__ W2, const float* __restrict__ b2,
    float* __restrict__ scores)
{
    const int bt = blockIdx.y;
    const int base = bondOff[bt];
    const int cnt  = bondOff[bt + 1] - base;
    const int t0 = blockIdx.x * TILE;
    if (t0 >= cnt) return;
    const int ne = min(TILE, cnt - t0);

    __shared__ __align__(16) unsigned char xs[64 * 256];      // 64 edges x 128 bf16, XOR-swizzled
    __shared__ __align__(16) unsigned char h0s[4][64 * 128];  // per-wave H0: 64x64 bf16, swizzled
    __shared__ int eids[TILE];

    const int tid = threadIdx.x;
    if (tid < TILE) eids[tid] = (tid < ne) ? bond_edges[base + t0 + tid] : 0;
    __syncthreads();

    // gather x = [Q[s] | K[d]] as bf16 into swizzled LDS (16B units)
    for (int i = tid; i < 1024; i += 256) {
        const int el = i >> 4, u = i & 15;
        uint4 v = make_uint4(0, 0, 0, 0);
        if (el < ne) {
            const int e = eids[el];
            int s, d;
            if (e < Ep) { s = src[e]; d = dst[e]; }
            else        { s = dst[e - Ep]; d = src[e - Ep]; }
            v = (u < 8) ? ((const uint4*)(Qbf + s * 64))[u]
                        : ((const uint4*)(Kbf + d * 64))[u - 8];
        }
        const int b = (el << 8) + (u << 4);
        *(uint4*)(xs + (b ^ ((el & 7) << 4))) = v;
    }
    __syncthreads();

    const int lane = tid & 63;
    const int h = tid >> 6;          // wave = head
    const int bh = bt * H + h;
    const int lg = lane >> 4;        // 0..3
    const int lr = lane & 15;        // 0..15

    // ---- layer 0: H0 = relu(X @ W0 + b0), K=128 ----
    f32x4 acc[4][4];
    const float* bb0 = b0 + bh * HID;
#pragma unroll
    for (int nt = 0; nt < 4; ++nt) {
        const float bv = bb0[(nt << 4) + lr];
#pragma unroll
        for (int mt = 0; mt < 4; ++mt) acc[mt][nt] = (f32x4){bv, bv, bv, bv};
    }
    const short8* W0f = (const short8*)W0p + (size_t)bh * 1024;
#pragma unroll
    for (int ks = 0; ks < 4; ++ks) {
        short8 a[4];
        const int koff = (ks << 6) + (lg << 4);
#pragma unroll
        for (int mt = 0; mt < 4; ++mt) {
            const int row = (mt << 4) + lr;
            const int b = (row << 8) + koff;
            a[mt] = *(const short8*)(xs + (b ^ ((row & 7) << 4)));
        }
        short8 bfr[4];
#pragma unroll
        for (int nt = 0; nt < 4; ++nt) bfr[nt] = W0f[(((ks << 2) + nt) << 6) + lane];
#pragma unroll
        for (int mt = 0; mt < 4; ++mt)
#pragma unroll
            for (int nt = 0; nt < 4; ++nt)
                acc[mt][nt] = __builtin_amdgcn_mfma_f32_16x16x32_bf16(a[mt], bfr[nt], acc[mt][nt], 0, 0, 0);
    }
    // relu -> per-wave LDS (bf16, swizzled) for layer-1 A fragments
    unsigned char* h0 = h0s[h];
#pragma unroll
    for (int mt = 0; mt < 4; ++mt)
#pragma unroll
        for (int nt = 0; nt < 4; ++nt)
#pragma unroll
            for (int r = 0; r < 4; ++r) {
                const int row = (mt << 4) + (lg << 2) + r;
                const int col = (nt << 4) + lr;
                const int b = (row << 7) + (col << 1);
                *(unsigned short*)(h0 + (b ^ ((row & 7) << 4))) = f2bf(fmaxf(acc[mt][nt][r], 0.f));
            }

    // ---- layer 1: H1 = relu(H0 @ W1 + b1), K=64 ----
    f32x4 acc1[4][4];
    const float* bb1 = b1 + bh * HID;
#pragma unroll
    for (int nt = 0; nt < 4; ++nt) {
        const float bv = bb1[(nt << 4) + lr];
#pragma unroll
        for (int mt = 0; mt < 4; ++mt) acc1[mt][nt] = (f32x4){bv, bv, bv, bv};
    }
    const short8* W1f = (const short8*)W1p + (size_t)bh * 512;
#pragma unroll
    for (int ks = 0; ks < 2; ++ks) {
        short8 a[4];
        const int koff = (ks << 6) + (lg << 4);
#pragma unroll
        for (int mt = 0; mt < 4; ++mt) {
            const int row = (mt << 4) + lr;
            const int b = (row << 7) + koff;
            a[mt] = *(const short8*)(h0 + (b ^ ((row & 7) << 4)));
        }
        short8 bfr[4];
#pragma unroll
        for (int nt = 0; nt < 4; ++nt) bfr[nt] = W1f[(((ks << 2) + nt) << 6) + lane];
#pragma unroll
        for (int mt = 0; mt < 4; ++mt)
#pragma unroll
            for (int nt = 0; nt < 4; ++nt)
                acc1[mt][nt] = __builtin_amdgcn_mfma_f32_16x16x32_bf16(a[mt], bfr[nt], acc1[mt][nt], 0, 0, 0);
    }

    // ---- layer 2: sc = relu(H1) . w2 + b2, leaky-relu; in-register 16-lane reduce ----
    const float* w2 = W2 + bh * HID;
    float w2v[4];
#pragma unroll
    for (int nt = 0; nt < 4; ++nt) w2v[nt] = w2[(nt << 4) + lr];
    float p[4][4];
#pragma unroll
    for (int mt = 0; mt < 4; ++mt)
#pragma unroll
        for (int r = 0; r < 4; ++r) {
            float s = 0.f;
#pragma unroll
            for (int nt = 0; nt < 4; ++nt) s += fmaxf(acc1[mt][nt][r], 0.f) * w2v[nt];
            p[mt][r] = s;
        }
#pragma unroll
    for (int off = 1; off <= 8; off <<= 1)
#pragma unroll
        for (int mt = 0; mt < 4; ++mt)
#pragma unroll
            for (int r = 0; r < 4; ++r) p[mt][r] += __shfl_xor(p[mt][r], off, 64);
    // lane (lg,lr) writes edge = (lr>>2)*16 + lg*4 + (lr&3)
    const int e_w = ((lr >> 2) << 4) + (lg << 2) + (lr & 3);
    float sc = p[lr >> 2][lr & 3] + b2[bh];
    sc = sc > 0.f ? sc : NEG_SLOPE * sc;
    if (e_w < ne) scores[(size_t)eids[e_w] * H + h] = sc;
}

// ---------------- softmax + V aggregation: 256 threads, wave = head ----------------
__global__ __launch_bounds__(256) void agg_kernel(
    const float* __restrict__ V, const float* __restrict__ scores,
    const int* __restrict__ rowStart, const int* __restrict__ edge_col,
    const int* __restrict__ edge_eid, float* __restrict__ out_attn)
{
    const int row = blockIdx.x;
    const int tid = threadIdx.x;
    const int lane = tid & 63;
    const int h = tid >> 6;
    const int beg = rowStart[row];
    int deg = rowStart[row + 1] - beg;
    if (deg > MAXDEG) deg = MAXDEG;

    __shared__ int tcol[MAXDEG], teid[MAXDEG];
    __shared__ int scol[MAXDEG], seid[MAXDEG];
    __shared__ int win[MAXDEG];
    __shared__ float wgt[4][MAXDEG];

    for (int a = tid; a < deg; a += 256) { tcol[a] = edge_col[beg + a]; teid[a] = edge_eid[beg + a]; }
    __syncthreads();
    // deterministic sort by (unique) global edge id via rank
    for (int a = tid; a < deg; a += 256) {
        const int e = teid[a];
        int r = 0;
        for (int b = 0; b < deg; ++b) r += (teid[b] < e);
        scol[r] = tcol[a];
        seid[r] = e;
    }
    __syncthreads();
    // winner = last occurrence of each column in edge-index order
    for (int a = tid; a < deg; a += 256) {
        const int c = scol[a];
        int wn = 1;
        for (int b = a + 1; b < deg; ++b) if (scol[b] == c) { wn = 0; break; }
        win[a] = wn;
    }
    __syncthreads();

    float m = -1e30f;
    for (int a = lane; a < deg; a += 64)
        if (win[a]) m = fmaxf(m, scores[(size_t)seid[a] * H + h]);
#pragma unroll
    for (int off = 32; off; off >>= 1) m = fmaxf(m, __shfl_xor(m, off, 64));

    float dn = 0.f;
    for (int a = lane; a < deg; a += 64) {
        const float wv = win[a] ? __expf(scores[(size_t)seid[a] * H + h] - m) : 0.f;
        wgt[h][a] = wv;
        dn += wv;
    }
#pragma unroll
    for (int off = 32; off; off >>= 1) dn += __shfl_xor(dn, off, 64);

    float accv = 0.f;
    for (int a = 0; a < deg; ++a) {
        const float wv = wgt[h][a];
        if (wv != 0.f) accv += wv * V[(size_t)scol[a] * D + lane];
    }
    out_attn[(size_t)row * (H * D) + h * D + lane] = accv / dn;
}

// ---------------- final projection: [N,256] @ [256,64] + Pb ----------------
__global__ void proj_kernel(const float* __restrict__ out_attn, const float* __restrict__ Pw,
                            const float* __restrict__ Pb, float* __restrict__ out)
{
    __shared__ float r[H * D];
    const int n = blockIdx.x, d = threadIdx.x;  // 64 threads
    for (int i = d; i < H * D; i += D) r[i] = out_attn[(size_t)n * (H * D) + i];
    __syncthreads();
    float acc = Pb[d];
#pragma unroll 8
    for (int k = 0; k < H * D; ++k) acc += r[k] * Pw[k * D + d];
    out[(size_t)n * D + d] = acc;
}

extern "C" void kernel_launch(void* const* d_in, const int* in_sizes, int n_in,
                              void* d_out, int out_size, void* d_ws, size_t ws_size,
                              hipStream_t stream)
{
    const float* emb = (const float*)d_in[0];
    const float* Qw  = (const float*)d_in[1];
    const float* Qb  = (const float*)d_in[2];
    const float* Kw  = (const float*)d_in[3];
    const float* Kb  = (const float*)d_in[4];
    const float* Vw  = (const float*)d_in[5];
    const float* Vb  = (const float*)d_in[6];
    const float* W0  = (const float*)d_in[7];
    const float* b0  = (const float*)d_in[8];
    const float* W1  = (const float*)d_in[9];
    const float* b1  = (const float*)d_in[10];
    const float* W2  = (const float*)d_in[11];
    const float* b2  = (const float*)d_in[12];
    const float* Pw  = (const float*)d_in[13];
    const float* Pb  = (const float*)d_in[14];
    const int* src   = (const int*)d_in[15];
    const int* dst   = (const int*)d_in[16];
    const int* bond  = (const int*)d_in[17];

    const int N  = in_sizes[0] / D;
    const int Ep = in_sizes[15];
    const int TE = 2 * Ep;

    // ---- workspace layout ----
    char* w = (char*)d_ws;
    auto alloc = [&](size_t bytes) -> void* {
        void* p = (void*)w;
        w += ((bytes + 255) / 256) * 256;
        return p;
    };
    unsigned short* Qbf = (unsigned short*)alloc((size_t)N * D * 2);
    unsigned short* Kbf = (unsigned short*)alloc((size_t)N * D * 2);
    float* V        = (float*)alloc((size_t)N * D * 4);
    unsigned short* W0p = (unsigned short*)alloc((size_t)131072 * 2);
    unsigned short* W1p = (unsigned short*)alloc((size_t)65536 * 2);
    float* scores   = (float*)alloc((size_t)TE * H * 4);
    float* out_attn = (float*)alloc((size_t)N * H * D * 4);
    int* rowStart   = (int*)alloc((size_t)(N + 1) * 4);
    int* bondOff    = (int*)alloc((size_t)(NB + 1) * 4);
    int* edge_col   = (int*)alloc((size_t)TE * 4);
    int* edge_eid   = (int*)alloc((size_t)TE * 4);
    int* bond_edges = (int*)alloc((size_t)TE * 4);
    int* counters   = (int*)alloc((size_t)(2 * N + 2 * NB) * 4);
    if ((size_t)(w - (char*)d_ws) > ws_size) return;

    int* rowCnt   = counters;
    int* rowFill  = counters + N;
    int* bondCnt  = counters + 2 * N;
    int* bondFill = counters + 2 * N + NB;

    hipMemsetAsync(counters, 0, (size_t)(2 * N + 2 * NB) * 4, stream);

    qkv_kernel<<<N, D, 0, stream>>>(emb, Qw, Qb, Kw, Kb, Vw, Vb, Qbf, Kbf, V);
    prepack_kernel<<<512, 256, 0, stream>>>(W0, W1, W0p, W1p);
    count_kernel<<<(TE + 255) / 256, 256, 0, stream>>>(src, dst, bond, Ep, rowCnt, bondCnt);
    scan_kernel<<<1, 1024, 0, stream>>>(rowCnt, rowStart, bondCnt, bondOff, N);
    scatter_kernel<<<(TE + 255) / 256, 256, 0, stream>>>(src, dst, bond, Ep, rowStart, rowFill,
                                                         bondOff, bondFill, edge_col, edge_eid,
                                                         bond_edges);
    dim3 mgrid((TE + TILE - 1) / TILE, NB);
    mlp_kernel<<<mgrid, 256, 0, stream>>>(Qbf, Kbf, src, dst, Ep, bondOff, bond_edges,
                                          W0p, W1p, b0, b1, W2, b2, scores);
    agg_kernel<<<N, 256, 0, stream>>>(V, scores, rowStart, edge_col, edge_eid, out_attn);
    proj_kernel<<<N, D, 0, stream>>>(out_attn, Pw, Pb, (float*)d_out);
}

// Round 4
// 108.090 us; speedup vs baseline: 13.5462x; 1.8334x over previous
//
#include <hip/hip_runtime.h>
#include <hip/hip_bf16.h>
#include <math.h>

#define D 64
#define H 4
#define NB 4
#define HID 64
#define TILE 64
#define MAXDEG 256
#define NEG_SLOPE 0.2f

typedef __attribute__((ext_vector_type(8))) short short8;
typedef __attribute__((ext_vector_type(4))) float f32x4;

__device__ __forceinline__ unsigned short f2bf(float f) {
    union { float f; unsigned int u; } c; c.f = f;
    const unsigned int u = c.u;
    return (unsigned short)((u + 0x7fffu + ((u >> 16) & 1u)) >> 16);
}

// ---------------- QKV: one block per node, 64 threads; Q,K as bf16, V fp32 ----------------
__global__ void qkv_kernel(const float* __restrict__ emb,
                           const float* __restrict__ Qw, const float* __restrict__ Qb,
                           const float* __restrict__ Kw, const float* __restrict__ Kb,
                           const float* __restrict__ Vw, const float* __restrict__ Vb,
                           unsigned short* __restrict__ Qbf, unsigned short* __restrict__ Kbf,
                           float* __restrict__ V)
{
    __shared__ float e[D];
    const int n = blockIdx.x, d = threadIdx.x;
    e[d] = emb[n * D + d];
    __syncthreads();
    float aq = Qb[d], ak = Kb[d], av = Vb[d];
#pragma unroll 8
    for (int k = 0; k < D; ++k) {
        const float x = e[k];
        aq += x * Qw[k * D + d];
        ak += x * Kw[k * D + d];
        av += x * Vw[k * D + d];
    }
    Qbf[n * D + d] = f2bf(aq);
    Kbf[n * D + d] = f2bf(ak);
    V[n * D + d] = av;
}

// ---------------- prepack weights into MFMA B-fragment order (bf16) ----------------
__global__ void prepack_kernel(const float* __restrict__ W0, const float* __restrict__ W1,
                               unsigned short* __restrict__ W0p, unsigned short* __restrict__ W1p)
{
    const int idx = blockIdx.x * 256 + threadIdx.x;
    if (idx < 131072) {
        const int j = idx & 7, lane = (idx >> 3) & 63, nt = (idx >> 9) & 3;
        const int ks = (idx >> 11) & 3, bh = idx >> 13;
        const int k = ks * 32 + ((lane >> 4) << 3) + j;
        const int n = (nt << 4) + (lane & 15);
        W0p[idx] = f2bf(W0[((size_t)bh * 128 + k) * 64 + n]);
    }
    if (idx < 65536) {
        const int j = idx & 7, lane = (idx >> 3) & 63, nt = (idx >> 9) & 3;
        const int ks = (idx >> 11) & 1, bh = idx >> 12;
        const int k = ks * 32 + ((lane >> 4) << 3) + j;
        const int n = (nt << 4) + (lane & 15);
        W1p[idx] = f2bf(W1[((size_t)bh * 64 + k) * 64 + n]);
    }
}

// ---------------- count: row atomics + per-block bond histogram (no bond atomics) ----------------
__global__ void count_kernel(const int* __restrict__ src, const int* __restrict__ dst,
                             const int* __restrict__ bond, int Ep,
                             int* __restrict__ rowCnt, int* __restrict__ blockBondCnt, int nblk)
{
    __shared__ int wcnt[4][NB];
    const int e = blockIdx.x * 256 + threadIdx.x;
    const int lane = threadIdx.x & 63;
    const int wave = threadIdx.x >> 6;
    const bool act = (e < 2 * Ep);
    int bt = -1;
    if (act) {
        const int s = (e < Ep) ? src[e] : dst[e - Ep];
        bt = (e < Ep) ? bond[e] : bond[e - Ep];
        atomicAdd(&rowCnt[s], 1);
    }
#pragma unroll
    for (int t = 0; t < NB; ++t) {
        const unsigned long long mask = __ballot(bt == t);
        if (lane == 0) wcnt[wave][t] = (int)__popcll(mask);
    }
    __syncthreads();
    if (threadIdx.x < NB) {
        int s = 0;
#pragma unroll
        for (int w = 0; w < 4; ++w) s += wcnt[w][threadIdx.x];
        blockBondCnt[threadIdx.x * nblk + blockIdx.x] = s;
    }
}

// ---------------- scans: rowStart (phase 1) + bond block bases (phase 2) ----------------
__global__ void scan_kernel(const int* __restrict__ rowCnt, int* __restrict__ rowStart,
                            const int* __restrict__ blockBondCnt, int* __restrict__ blockBondBase,
                            int* __restrict__ bondOff, int N, int nblk)
{
    __shared__ int part[1024];
    __shared__ int sbase[2048];
    const int t = threadIdx.x;

    // ---- phase 1: exclusive scan of rowCnt -> rowStart ----
    {
        const int base = t * 4;
        int loc[4];
        int s = 0;
#pragma unroll
        for (int i = 0; i < 4; ++i) {
            const int idx = base + i;
            const int v = (idx < N) ? rowCnt[idx] : 0;
            loc[i] = s;
            s += v;
        }
        part[t] = s;
        __syncthreads();
        int val = s;
        for (int off = 1; off < 1024; off <<= 1) {
            const int other = (t >= off) ? part[t - off] : 0;
            __syncthreads();
            val += other;
            part[t] = val;
            __syncthreads();
        }
        const int excl = val - s;
#pragma unroll
        for (int i = 0; i < 4; ++i) {
            const int idx = base + i;
            if (idx < N) rowStart[idx] = excl + loc[i];
        }
        if (t == 1023) rowStart[N] = val;
    }
    __syncthreads();

    // ---- phase 2: exclusive scan of blockBondCnt (type-major, NB*nblk) ----
    {
        const int M = NB * nblk;  // <= 2048
        int loc[2];
        int s = 0;
#pragma unroll
        for (int i = 0; i < 2; ++i) {
            const int idx = t * 2 + i;
            const int v = (idx < M) ? blockBondCnt[idx] : 0;
            loc[i] = s;
            s += v;
        }
        part[t] = s;
        __syncthreads();
        int val = s;
        for (int off = 1; off < 1024; off <<= 1) {
            const int other = (t >= off) ? part[t - off] : 0;
            __syncthreads();
            val += other;
            part[t] = val;
            __syncthreads();
        }
        const int excl = val - s;
#pragma unroll
        for (int i = 0; i < 2; ++i) {
            const int idx = t * 2 + i;
            if (idx < M) sbase[idx] = excl + loc[i];
        }
        if (t == 1023) bondOff[NB] = val;  // grand total
        __syncthreads();
#pragma unroll
        for (int i = 0; i < 2; ++i) {
            const int idx = t * 2 + i;
            if (idx < M) blockBondBase[idx] = sbase[idx];
        }
        if (t == 0) {
            bondOff[0] = 0;
            for (int b = 1; b < NB; ++b) bondOff[b] = sbase[b * nblk];
        }
    }
}

// ---------------- scatter: row-CSR via row atomics; bond buckets via precomputed bases ----------------
__global__ void scatter_kernel(const int* __restrict__ src, const int* __restrict__ dst,
                               const int* __restrict__ bond, int Ep,
                               const int* __restrict__ rowStart, int* __restrict__ rowFill,
                               const int* __restrict__ blockBondBase, int nblk,
                               int* __restrict__ edge_col, int* __restrict__ edge_eid,
                               int* __restrict__ bond_edges)
{
    __shared__ int wcnt[4][NB];
    __shared__ int wbase[4][NB];
    const int e = blockIdx.x * 256 + threadIdx.x;
    const int lane = threadIdx.x & 63;
    const int wave = threadIdx.x >> 6;
    const bool act = (e < 2 * Ep);
    int s = 0, d = 0, bt = -1;
    if (act) {
        if (e < Ep) { s = src[e]; d = dst[e]; bt = bond[e]; }
        else        { s = dst[e - Ep]; d = src[e - Ep]; bt = bond[e - Ep]; }
        const int p = rowStart[s] + atomicAdd(&rowFill[s], 1);
        edge_col[p] = d;
        edge_eid[p] = e;
    }
    int myrank = 0;
#pragma unroll
    for (int t = 0; t < NB; ++t) {
        const unsigned long long mask = __ballot(bt == t);
        if (lane == 0) wcnt[wave][t] = (int)__popcll(mask);
        if (bt == t) myrank = (int)__popcll(mask & ((1ull << lane) - 1ull));
    }
    __syncthreads();
    if (threadIdx.x < NB) {
        int sum = 0;
#pragma unroll
        for (int w = 0; w < 4; ++w) { wbase[w][threadIdx.x] = sum; sum += wcnt[w][threadIdx.x]; }
    }
    __syncthreads();
    if (act) {
        const int q = blockBondBase[bt * nblk + blockIdx.x] + wbase[wave][bt] + myrank;
        bond_edges[q] = e;
    }
}

// ---------------- MFMA grouped edge MLP: 64-edge tile per bond, 4 waves = 4 heads ----------------
__global__ __launch_bounds__(256) void mlp_kernel(
    const unsigned short* __restrict__ Qbf, const unsigned short* __restrict__ Kbf,
    const int* __restrict__ src, const int* __restrict__ dst, int Ep,
    const int* __restrict__ bondOff, const int* __restrict__ bond_edges,
    const unsigned short* __restrict__ W0p, const unsigned short* __restrict__ W1p,
    const float* __restrict__ b0, const float* __restrict__ b1,
    const float* __restrict__ W2, const float* __restrict__ b2,
    float* __restrict__ scores)
{
    const int bt = blockIdx.y;
    const int base = bondOff[bt];
    const int cnt  = bondOff[bt + 1] - base;
    const int t0 = blockIdx.x * TILE;
    if (t0 >= cnt) return;
    const int ne = min(TILE, cnt - t0);

    __shared__ __align__(16) unsigned char xs[64 * 256];      // 64 edges x 128 bf16, XOR-swizzled
    __shared__ __align__(16) unsigned char h0s[4][64 * 128];  // per-wave H0: 64x64 bf16, swizzled
    __shared__ int eids[TILE];

    const int tid = threadIdx.x;
    if (tid < TILE) eids[tid] = (tid < ne) ? bond_edges[base + t0 + tid] : 0;
    __syncthreads();

    // gather x = [Q[s] | K[d]] as bf16 into swizzled LDS (16B units)
    for (int i = tid; i < 1024; i += 256) {
        const int el = i >> 4, u = i & 15;
        uint4 v = make_uint4(0, 0, 0, 0);
        if (el < ne) {
            const int e = eids[el];
            int s, d;
            if (e < Ep) { s = src[e]; d = dst[e]; }
            else        { s = dst[e - Ep]; d = src[e - Ep]; }
            v = (u < 8) ? ((const uint4*)(Qbf + s * 64))[u]
                        : ((const uint4*)(Kbf + d * 64))[u - 8];
        }
        const int b = (el << 8) + (u << 4);
        *(uint4*)(xs + (b ^ ((el & 7) << 4))) = v;
    }
    __syncthreads();

    const int lane = tid & 63;
    const int h = tid >> 6;          // wave = head
    const int bh = bt * H + h;
    const int lg = lane >> 4;        // 0..3
    const int lr = lane & 15;        // 0..15

    // ---- layer 0: H0 = relu(X @ W0 + b0), K=128 ----
    f32x4 acc[4][4];
    const float* bb0 = b0 + bh * HID;
#pragma unroll
    for (int nt = 0; nt < 4; ++nt) {
        const float bv = bb0[(nt << 4) + lr];
#pragma unroll
        for (int mt = 0; mt < 4; ++mt) acc[mt][nt] = (f32x4){bv, bv, bv, bv};
    }
    const short8* W0f = (const short8*)W0p + (size_t)bh * 1024;
#pragma unroll
    for (int ks = 0; ks < 4; ++ks) {
        short8 a[4];
        const int koff = (ks << 6) + (lg << 4);
#pragma unroll
        for (int mt = 0; mt < 4; ++mt) {
            const int row = (mt << 4) + lr;
            const int b = (row << 8) + koff;
            a[mt] = *(const short8*)(xs + (b ^ ((row & 7) << 4)));
        }
        short8 bfr[4];
#pragma unroll
        for (int nt = 0; nt < 4; ++nt) bfr[nt] = W0f[(((ks << 2) + nt) << 6) + lane];
#pragma unroll
        for (int mt = 0; mt < 4; ++mt)
#pragma unroll
            for (int nt = 0; nt < 4; ++nt)
                acc[mt][nt] = __builtin_amdgcn_mfma_f32_16x16x32_bf16(a[mt], bfr[nt], acc[mt][nt], 0, 0, 0);
    }
    // relu -> per-wave LDS (bf16, swizzled) for layer-1 A fragments
    unsigned char* h0 = h0s[h];
#pragma unroll
    for (int mt = 0; mt < 4; ++mt)
#pragma unroll
        for (int nt = 0; nt < 4; ++nt)
#pragma unroll
            for (int r = 0; r < 4; ++r) {
                const int row = (mt << 4) + (lg << 2) + r;
                const int col = (nt << 4) + lr;
                const int b = (row << 7) + (col << 1);
                *(unsigned short*)(h0 + (b ^ ((row & 7) << 4))) = f2bf(fmaxf(acc[mt][nt][r], 0.f));
            }

    // ---- layer 1: H1 = relu(H0 @ W1 + b1), K=64 ----
    f32x4 acc1[4][4];
    const float* bb1 = b1 + bh * HID;
#pragma unroll
    for (int nt = 0; nt < 4; ++nt) {
        const float bv = bb1[(nt << 4) + lr];
#pragma unroll
        for (int mt = 0; mt < 4; ++mt) acc1[mt][nt] = (f32x4){bv, bv, bv, bv};
    }
    const short8* W1f = (const short8*)W1p + (size_t)bh * 512;
#pragma unroll
    for (int ks = 0; ks < 2; ++ks) {
        short8 a[4];
        const int koff = (ks << 6) + (lg << 4);
#pragma unroll
        for (int mt = 0; mt < 4; ++mt) {
            const int row = (mt << 4) + lr;
            const int b = (row << 7) + koff;
            a[mt] = *(const short8*)(h0 + (b ^ ((row & 7) << 4)));
        }
        short8 bfr[4];
#pragma unroll
        for (int nt = 0; nt < 4; ++nt) bfr[nt] = W1f[(((ks << 2) + nt) << 6) + lane];
#pragma unroll
        for (int mt = 0; mt < 4; ++mt)
#pragma unroll
            for (int nt = 0; nt < 4; ++nt)
                acc1[mt][nt] = __builtin_amdgcn_mfma_f32_16x16x32_bf16(a[mt], bfr[nt], acc1[mt][nt], 0, 0, 0);
    }

    // ---- layer 2: sc = relu(H1) . w2 + b2, leaky-relu; in-register 16-lane reduce ----
    const float* w2 = W2 + bh * HID;
    float w2v[4];
#pragma unroll
    for (int nt = 0; nt < 4; ++nt) w2v[nt] = w2[(nt << 4) + lr];
    float p[4][4];
#pragma unroll
    for (int mt = 0; mt < 4; ++mt)
#pragma unroll
        for (int r = 0; r < 4; ++r) {
            float s = 0.f;
#pragma unroll
            for (int nt = 0; nt < 4; ++nt) s += fmaxf(acc1[mt][nt][r], 0.f) * w2v[nt];
            p[mt][r] = s;
        }
#pragma unroll
    for (int off = 1; off <= 8; off <<= 1)
#pragma unroll
        for (int mt = 0; mt < 4; ++mt)
#pragma unroll
            for (int r = 0; r < 4; ++r) p[mt][r] += __shfl_xor(p[mt][r], off, 64);
    // lane (lg,lr) writes edge = (lr>>2)*16 + lg*4 + (lr&3)
    const int e_w = ((lr >> 2) << 4) + (lg << 2) + (lr & 3);
    float sc = p[lr >> 2][lr & 3] + b2[bh];
    sc = sc > 0.f ? sc : NEG_SLOPE * sc;
    if (e_w < ne) scores[(size_t)eids[e_w] * H + h] = sc;
}

// ---------------- softmax + V aggregation: 256 threads, wave = head ----------------
__global__ __launch_bounds__(256) void agg_kernel(
    const float* __restrict__ V, const float* __restrict__ scores,
    const int* __restrict__ rowStart, const int* __restrict__ edge_col,
    const int* __restrict__ edge_eid, float* __restrict__ out_attn)
{
    const int row = blockIdx.x;
    const int tid = threadIdx.x;
    const int lane = tid & 63;
    const int h = tid >> 6;
    const int beg = rowStart[row];
    int deg = rowStart[row + 1] - beg;
    if (deg > MAXDEG) deg = MAXDEG;

    __shared__ int tcol[MAXDEG], teid[MAXDEG];
    __shared__ int scol[MAXDEG], seid[MAXDEG];
    __shared__ int win[MAXDEG];
    __shared__ float wgt[4][MAXDEG];

    for (int a = tid; a < deg; a += 256) { tcol[a] = edge_col[beg + a]; teid[a] = edge_eid[beg + a]; }
    __syncthreads();
    // deterministic sort by (unique) global edge id via rank
    for (int a = tid; a < deg; a += 256) {
        const int e = teid[a];
        int r = 0;
        for (int b = 0; b < deg; ++b) r += (teid[b] < e);
        scol[r] = tcol[a];
        seid[r] = e;
    }
    __syncthreads();
    // winner = last occurrence of each column in edge-index order
    for (int a = tid; a < deg; a += 256) {
        const int c = scol[a];
        int wn = 1;
        for (int b = a + 1; b < deg; ++b) if (scol[b] == c) { wn = 0; break; }
        win[a] = wn;
    }
    __syncthreads();

    float m = -1e30f;
    for (int a = lane; a < deg; a += 64)
        if (win[a]) m = fmaxf(m, scores[(size_t)seid[a] * H + h]);
#pragma unroll
    for (int off = 32; off; off >>= 1) m = fmaxf(m, __shfl_xor(m, off, 64));

    float dn = 0.f;
    for (int a = lane; a < deg; a += 64) {
        const float wv = win[a] ? __expf(scores[(size_t)seid[a] * H + h] - m) : 0.f;
        wgt[h][a] = wv;
        dn += wv;
    }
#pragma unroll
    for (int off = 32; off; off >>= 1) dn += __shfl_xor(dn, off, 64);

    float accv = 0.f;
    for (int a = 0; a < deg; ++a) {
        const float wv = wgt[h][a];
        if (wv != 0.f) accv += wv * V[(size_t)scol[a] * D + lane];
    }
    out_attn[(size_t)row * (H * D) + h * D + lane] = accv / dn;
}

// ---------------- final projection: [N,256] @ [256,64] + Pb ----------------
__global__ void proj_kernel(const float* __restrict__ out_attn, const float* __restrict__ Pw,
                            const float* __restrict__ Pb, float* __restrict__ out)
{
    __shared__ float r[H * D];
    const int n = blockIdx.x, d = threadIdx.x;  // 64 threads
    for (int i = d; i < H * D; i += D) r[i] = out_attn[(size_t)n * (H * D) + i];
    __syncthreads();
    float acc = Pb[d];
#pragma unroll 8
    for (int k = 0; k < H * D; ++k) acc += r[k] * Pw[k * D + d];
    out[(size_t)n * D + d] = acc;
}

extern "C" void kernel_launch(void* const* d_in, const int* in_sizes, int n_in,
                              void* d_out, int out_size, void* d_ws, size_t ws_size,
                              hipStream_t stream)
{
    const float* emb = (const float*)d_in[0];
    const float* Qw  = (const float*)d_in[1];
    const float* Qb  = (const float*)d_in[2];
    const float* Kw  = (const float*)d_in[3];
    const float* Kb  = (const float*)d_in[4];
    const float* Vw  = (const float*)d_in[5];
    const float* Vb  = (const float*)d_in[6];
    const float* W0  = (const float*)d_in[7];
    const float* b0  = (const float*)d_in[8];
    const float* W1  = (const float*)d_in[9];
    const float* b1  = (const float*)d_in[10];
    const float* W2  = (const float*)d_in[11];
    const float* b2  = (const float*)d_in[12];
    const float* Pw  = (const float*)d_in[13];
    const float* Pb  = (const float*)d_in[14];
    const int* src   = (const int*)d_in[15];
    const int* dst   = (const int*)d_in[16];
    const int* bond  = (const int*)d_in[17];

    const int N  = in_sizes[0] / D;
    const int Ep = in_sizes[15];
    const int TE = 2 * Ep;
    const int nblk = (TE + 255) / 256;

    // ---- workspace layout ----
    char* w = (char*)d_ws;
    auto alloc = [&](size_t bytes) -> void* {
        void* p = (void*)w;
        w += ((bytes + 255) / 256) * 256;
        return p;
    };
    unsigned short* Qbf = (unsigned short*)alloc((size_t)N * D * 2);
    unsigned short* Kbf = (unsigned short*)alloc((size_t)N * D * 2);
    float* V        = (float*)alloc((size_t)N * D * 4);
    unsigned short* W0p = (unsigned short*)alloc((size_t)131072 * 2);
    unsigned short* W1p = (unsigned short*)alloc((size_t)65536 * 2);
    float* scores   = (float*)alloc((size_t)TE * H * 4);
    float* out_attn = (float*)alloc((size_t)N * H * D * 4);
    int* rowStart   = (int*)alloc((size_t)(N + 1) * 4);
    int* bondOff    = (int*)alloc((size_t)(NB + 1) * 4);
    int* edge_col   = (int*)alloc((size_t)TE * 4);
    int* edge_eid   = (int*)alloc((size_t)TE * 4);
    int* bond_edges = (int*)alloc((size_t)TE * 4);
    int* blockBondCnt  = (int*)alloc((size_t)NB * nblk * 4);
    int* blockBondBase = (int*)alloc((size_t)NB * nblk * 4);
    int* counters   = (int*)alloc((size_t)(2 * N) * 4);
    if ((size_t)(w - (char*)d_ws) > ws_size) return;

    int* rowCnt  = counters;
    int* rowFill = counters + N;

    hipMemsetAsync(counters, 0, (size_t)(2 * N) * 4, stream);

    qkv_kernel<<<N, D, 0, stream>>>(emb, Qw, Qb, Kw, Kb, Vw, Vb, Qbf, Kbf, V);
    prepack_kernel<<<512, 256, 0, stream>>>(W0, W1, W0p, W1p);
    count_kernel<<<nblk, 256, 0, stream>>>(src, dst, bond, Ep, rowCnt, blockBondCnt, nblk);
    scan_kernel<<<1, 1024, 0, stream>>>(rowCnt, rowStart, blockBondCnt, blockBondBase,
                                        bondOff, N, nblk);
    scatter_kernel<<<nblk, 256, 0, stream>>>(src, dst, bond, Ep, rowStart, rowFill,
                                             blockBondBase, nblk, edge_col, edge_eid,
                                             bond_edges);
    dim3 mgrid((TE + TILE - 1) / TILE, NB);
    mlp_kernel<<<mgrid, 256, 0, stream>>>(Qbf, Kbf, src, dst, Ep, bondOff, bond_edges,
                                          W0p, W1p, b0, b1, W2, b2, scores);
    agg_kernel<<<N, 256, 0, stream>>>(V, scores, rowStart, edge_col, edge_eid, out_attn);
    proj_kernel<<<N, D, 0, stream>>>(out_attn, Pw, Pb, (float*)d_out);
}

// Round 5
// 101.280 us; speedup vs baseline: 14.4571x; 1.0672x over previous
//
#include <hip/hip_runtime.h>
#include <hip/hip_bf16.h>
#include <math.h>

#define D 64
#define H 4
#define NB 4
#define HID 64
#define TILE 64
#define MAXDEG 256
#define NEG_SLOPE 0.2f

typedef __attribute__((ext_vector_type(8))) short short8;
typedef __attribute__((ext_vector_type(4))) float f32x4;

__device__ __forceinline__ unsigned short f2bf(float f) {
    union { float f; unsigned int u; } c; c.f = f;
    const unsigned int u = c.u;
    return (unsigned short)((u + 0x7fffu + ((u >> 16) & 1u)) >> 16);
}

// ---------------- prep: zero counters + QKV (4 nodes/block) + weight prepack, one launch ----------------
__global__ __launch_bounds__(256) void prep_kernel(
    const float* __restrict__ emb,
    const float* __restrict__ Qw, const float* __restrict__ Qb,
    const float* __restrict__ Kw, const float* __restrict__ Kb,
    const float* __restrict__ Vw, const float* __restrict__ Vb,
    unsigned short* __restrict__ Qbf, unsigned short* __restrict__ Kbf,
    float* __restrict__ V,
    const float* __restrict__ W0, const float* __restrict__ W1,
    unsigned short* __restrict__ W0p, unsigned short* __restrict__ W1p,
    int* __restrict__ counters, int N, int nq)
{
    const int tid = threadIdx.x;
    if (blockIdx.x < nq) {
        // zero rowCnt/rowFill (2N ints; nq*256 >= 2N for N>=... always here)
        const int gz = blockIdx.x * 256 + tid;
        if (gz < 2 * N) counters[gz] = 0;

        __shared__ float e[4][64];
        const int n = blockIdx.x * 4 + (tid >> 6);
        const int d = tid & 63;
        if (n < N) e[tid >> 6][d] = emb[n * D + d];
        __syncthreads();
        if (n < N) {
            float aq = Qb[d], ak = Kb[d], av = Vb[d];
            const float* er = e[tid >> 6];
#pragma unroll 8
            for (int k = 0; k < D; ++k) {
                const float x = er[k];
                aq += x * Qw[k * D + d];
                ak += x * Kw[k * D + d];
                av += x * Vw[k * D + d];
            }
            Qbf[n * D + d] = f2bf(aq);
            Kbf[n * D + d] = f2bf(ak);
            V[n * D + d] = av;
        }
    } else {
        const int idx = (blockIdx.x - nq) * 256 + tid;
        if (idx < 131072) {
            const int j = idx & 7, lane = (idx >> 3) & 63, nt = (idx >> 9) & 3;
            const int ks = (idx >> 11) & 3, bh = idx >> 13;
            const int k = ks * 32 + ((lane >> 4) << 3) + j;
            const int nn = (nt << 4) + (lane & 15);
            W0p[idx] = f2bf(W0[((size_t)bh * 128 + k) * 64 + nn]);
        }
        if (idx < 65536) {
            const int j = idx & 7, lane = (idx >> 3) & 63, nt = (idx >> 9) & 3;
            const int ks = (idx >> 11) & 1, bh = idx >> 12;
            const int k = ks * 32 + ((lane >> 4) << 3) + j;
            const int nn = (nt << 4) + (lane & 15);
            W1p[idx] = f2bf(W1[((size_t)bh * 64 + k) * 64 + nn]);
        }
    }
}

// ---------------- count: row atomics + per-block bond histogram (no bond atomics) ----------------
__global__ void count_kernel(const int* __restrict__ src, const int* __restrict__ dst,
                             const int* __restrict__ bond, int Ep,
                             int* __restrict__ rowCnt, int* __restrict__ blockBondCnt, int nblk)
{
    __shared__ int wcnt[4][NB];
    const int e = blockIdx.x * 256 + threadIdx.x;
    const int lane = threadIdx.x & 63;
    const int wave = threadIdx.x >> 6;
    const bool act = (e < 2 * Ep);
    int bt = -1;
    if (act) {
        const int s = (e < Ep) ? src[e] : dst[e - Ep];
        bt = (e < Ep) ? bond[e] : bond[e - Ep];
        atomicAdd(&rowCnt[s], 1);
    }
#pragma unroll
    for (int t = 0; t < NB; ++t) {
        const unsigned long long mask = __ballot(bt == t);
        if (lane == 0) wcnt[wave][t] = (int)__popcll(mask);
    }
    __syncthreads();
    if (threadIdx.x < NB) {
        int s = 0;
#pragma unroll
        for (int w = 0; w < 4; ++w) s += wcnt[w][threadIdx.x];
        blockBondCnt[threadIdx.x * nblk + blockIdx.x] = s;
    }
}

// ---------------- scans: rowStart (phase 1) + bond block bases (phase 2) ----------------
__global__ void scan_kernel(const int* __restrict__ rowCnt, int* __restrict__ rowStart,
                            const int* __restrict__ blockBondCnt, int* __restrict__ blockBondBase,
                            int* __restrict__ bondOff, int N, int nblk)
{
    __shared__ int part[1024];
    __shared__ int sbase[2048];
    const int t = threadIdx.x;

    // ---- phase 1: exclusive scan of rowCnt -> rowStart ----
    {
        const int base = t * 4;
        int loc[4];
        int s = 0;
#pragma unroll
        for (int i = 0; i < 4; ++i) {
            const int idx = base + i;
            const int v = (idx < N) ? rowCnt[idx] : 0;
            loc[i] = s;
            s += v;
        }
        part[t] = s;
        __syncthreads();
        int val = s;
        for (int off = 1; off < 1024; off <<= 1) {
            const int other = (t >= off) ? part[t - off] : 0;
            __syncthreads();
            val += other;
            part[t] = val;
            __syncthreads();
        }
        const int excl = val - s;
#pragma unroll
        for (int i = 0; i < 4; ++i) {
            const int idx = base + i;
            if (idx < N) rowStart[idx] = excl + loc[i];
        }
        if (t == 1023) rowStart[N] = val;
    }
    __syncthreads();

    // ---- phase 2: exclusive scan of blockBondCnt (type-major, NB*nblk) ----
    {
        const int M = NB * nblk;  // <= 2048
        int loc[2];
        int s = 0;
#pragma unroll
        for (int i = 0; i < 2; ++i) {
            const int idx = t * 2 + i;
            const int v = (idx < M) ? blockBondCnt[idx] : 0;
            loc[i] = s;
            s += v;
        }
        part[t] = s;
        __syncthreads();
        int val = s;
        for (int off = 1; off < 1024; off <<= 1) {
            const int other = (t >= off) ? part[t - off] : 0;
            __syncthreads();
            val += other;
            part[t] = val;
            __syncthreads();
        }
        const int excl = val - s;
#pragma unroll
        for (int i = 0; i < 2; ++i) {
            const int idx = t * 2 + i;
            if (idx < M) sbase[idx] = excl + loc[i];
        }
        if (t == 1023) bondOff[NB] = val;  // grand total
        __syncthreads();
#pragma unroll
        for (int i = 0; i < 2; ++i) {
            const int idx = t * 2 + i;
            if (idx < M) blockBondBase[idx] = sbase[idx];
        }
        if (t == 0) {
            bondOff[0] = 0;
            for (int b = 1; b < NB; ++b) bondOff[b] = sbase[b * nblk];
        }
    }
}

// ---------------- scatter: row-CSR via row atomics; bond buckets via precomputed bases ----------------
__global__ void scatter_kernel(const int* __restrict__ src, const int* __restrict__ dst,
                               const int* __restrict__ bond, int Ep,
                               const int* __restrict__ rowStart, int* __restrict__ rowFill,
                               const int* __restrict__ blockBondBase, int nblk,
                               int* __restrict__ edge_col, int* __restrict__ edge_eid,
                               int* __restrict__ bond_edges)
{
    __shared__ int wcnt[4][NB];
    __shared__ int wbase[4][NB];
    const int e = blockIdx.x * 256 + threadIdx.x;
    const int lane = threadIdx.x & 63;
    const int wave = threadIdx.x >> 6;
    const bool act = (e < 2 * Ep);
    int s = 0, d = 0, bt = -1;
    if (act) {
        if (e < Ep) { s = src[e]; d = dst[e]; bt = bond[e]; }
        else        { s = dst[e - Ep]; d = src[e - Ep]; bt = bond[e - Ep]; }
        const int p = rowStart[s] + atomicAdd(&rowFill[s], 1);
        edge_col[p] = d;
        edge_eid[p] = e;
    }
    int myrank = 0;
#pragma unroll
    for (int t = 0; t < NB; ++t) {
        const unsigned long long mask = __ballot(bt == t);
        if (lane == 0) wcnt[wave][t] = (int)__popcll(mask);
        if (bt == t) myrank = (int)__popcll(mask & ((1ull << lane) - 1ull));
    }
    __syncthreads();
    if (threadIdx.x < NB) {
        int sum = 0;
#pragma unroll
        for (int w = 0; w < 4; ++w) { wbase[w][threadIdx.x] = sum; sum += wcnt[w][threadIdx.x]; }
    }
    __syncthreads();
    if (act) {
        const int q = blockBondBase[bt * nblk + blockIdx.x] + wbase[wave][bt] + myrank;
        bond_edges[q] = e;
    }
}

// ---------------- MFMA grouped edge MLP: 64-edge tile per bond, 4 waves = 4 heads ----------------
__global__ __launch_bounds__(256) void mlp_kernel(
    const unsigned short* __restrict__ Qbf, const unsigned short* __restrict__ Kbf,
    const int* __restrict__ src, const int* __restrict__ dst, int Ep,
    const int* __restrict__ bondOff, const int* __restrict__ bond_edges,
    const unsigned short* __restrict__ W0p, const unsigned short* __restrict__ W1p,
    const float* __restrict__ b0, const float* __restrict__ b1,
    const float* __restrict__ W2, const float* __restrict__ b2,
    float* __restrict__ scores)
{
    const int bt = blockIdx.y;
    const int base = bondOff[bt];
    const int cnt  = bondOff[bt + 1] - base;
    const int t0 = blockIdx.x * TILE;
    if (t0 >= cnt) return;
    const int ne = min(TILE, cnt - t0);

    __shared__ __align__(16) unsigned char xs[64 * 256];      // 64 edges x 128 bf16, XOR-swizzled
    __shared__ __align__(16) unsigned char h0s[4][64 * 128];  // per-wave H0: 64x64 bf16, swizzled
    __shared__ int eids[TILE];

    const int tid = threadIdx.x;
    if (tid < TILE) eids[tid] = (tid < ne) ? bond_edges[base + t0 + tid] : 0;
    __syncthreads();

    // gather x = [Q[s] | K[d]] as bf16 into swizzled LDS (16B units)
    for (int i = tid; i < 1024; i += 256) {
        const int el = i >> 4, u = i & 15;
        uint4 v = make_uint4(0, 0, 0, 0);
        if (el < ne) {
            const int e = eids[el];
            int s, d;
            if (e < Ep) { s = src[e]; d = dst[e]; }
            else        { s = dst[e - Ep]; d = src[e - Ep]; }
            v = (u < 8) ? ((const uint4*)(Qbf + s * 64))[u]
                        : ((const uint4*)(Kbf + d * 64))[u - 8];
        }
        const int b = (el << 8) + (u << 4);
        *(uint4*)(xs + (b ^ ((el & 7) << 4))) = v;
    }
    __syncthreads();

    const int lane = tid & 63;
    const int h = tid >> 6;          // wave = head
    const int bh = bt * H + h;
    const int lg = lane >> 4;        // 0..3
    const int lr = lane & 15;        // 0..15

    // ---- layer 0: H0 = relu(X @ W0 + b0), K=128 ----
    f32x4 acc[4][4];
    const float* bb0 = b0 + bh * HID;
#pragma unroll
    for (int nt = 0; nt < 4; ++nt) {
        const float bv = bb0[(nt << 4) + lr];
#pragma unroll
        for (int mt = 0; mt < 4; ++mt) acc[mt][nt] = (f32x4){bv, bv, bv, bv};
    }
    const short8* W0f = (const short8*)W0p + (size_t)bh * 1024;
#pragma unroll
    for (int ks = 0; ks < 4; ++ks) {
        short8 a[4];
        const int koff = (ks << 6) + (lg << 4);
#pragma unroll
        for (int mt = 0; mt < 4; ++mt) {
            const int row = (mt << 4) + lr;
            const int b = (row << 8) + koff;
            a[mt] = *(const short8*)(xs + (b ^ ((row & 7) << 4)));
        }
        short8 bfr[4];
#pragma unroll
        for (int nt = 0; nt < 4; ++nt) bfr[nt] = W0f[(((ks << 2) + nt) << 6) + lane];
#pragma unroll
        for (int mt = 0; mt < 4; ++mt)
#pragma unroll
            for (int nt = 0; nt < 4; ++nt)
                acc[mt][nt] = __builtin_amdgcn_mfma_f32_16x16x32_bf16(a[mt], bfr[nt], acc[mt][nt], 0, 0, 0);
    }
    // relu -> per-wave LDS (bf16, swizzled) for layer-1 A fragments
    unsigned char* h0 = h0s[h];
#pragma unroll
    for (int mt = 0; mt < 4; ++mt)
#pragma unroll
        for (int nt = 0; nt < 4; ++nt)
#pragma unroll
            for (int r = 0; r < 4; ++r) {
                const int row = (mt << 4) + (lg << 2) + r;
                const int col = (nt << 4) + lr;
                const int b = (row << 7) + (col << 1);
                *(unsigned short*)(h0 + (b ^ ((row & 7) << 4))) = f2bf(fmaxf(acc[mt][nt][r], 0.f));
            }

    // ---- layer 1: H1 = relu(H0 @ W1 + b1), K=64 ----
    f32x4 acc1[4][4];
    const float* bb1 = b1 + bh * HID;
#pragma unroll
    for (int nt = 0; nt < 4; ++nt) {
        const float bv = bb1[(nt << 4) + lr];
#pragma unroll
        for (int mt = 0; mt < 4; ++mt) acc1[mt][nt] = (f32x4){bv, bv, bv, bv};
    }
    const short8* W1f = (const short8*)W1p + (size_t)bh * 512;
#pragma unroll
    for (int ks = 0; ks < 2; ++ks) {
        short8 a[4];
        const int koff = (ks << 6) + (lg << 4);
#pragma unroll
        for (int mt = 0; mt < 4; ++mt) {
            const int row = (mt << 4) + lr;
            const int b = (row << 7) + koff;
            a[mt] = *(const short8*)(h0 + (b ^ ((row & 7) << 4)));
        }
        short8 bfr[4];
#pragma unroll
        for (int nt = 0; nt < 4; ++nt) bfr[nt] = W1f[(((ks << 2) + nt) << 6) + lane];
#pragma unroll
        for (int mt = 0; mt < 4; ++mt)
#pragma unroll
            for (int nt = 0; nt < 4; ++nt)
                acc1[mt][nt] = __builtin_amdgcn_mfma_f32_16x16x32_bf16(a[mt], bfr[nt], acc1[mt][nt], 0, 0, 0);
    }

    // ---- layer 2: sc = relu(H1) . w2 + b2, leaky-relu; in-register 16-lane reduce ----
    const float* w2 = W2 + bh * HID;
    float w2v[4];
#pragma unroll
    for (int nt = 0; nt < 4; ++nt) w2v[nt] = w2[(nt << 4) + lr];
    float p[4][4];
#pragma unroll
    for (int mt = 0; mt < 4; ++mt)
#pragma unroll
        for (int r = 0; r < 4; ++r) {
            float s = 0.f;
#pragma unroll
            for (int nt = 0; nt < 4; ++nt) s += fmaxf(acc1[mt][nt][r], 0.f) * w2v[nt];
            p[mt][r] = s;
        }
#pragma unroll
    for (int off = 1; off <= 8; off <<= 1)
#pragma unroll
        for (int mt = 0; mt < 4; ++mt)
#pragma unroll
            for (int r = 0; r < 4; ++r) p[mt][r] += __shfl_xor(p[mt][r], off, 64);
    // lane (lg,lr) writes edge = (lr>>2)*16 + lg*4 + (lr&3)
    const int e_w = ((lr >> 2) << 4) + (lg << 2) + (lr & 3);
    float sc = p[lr >> 2][lr & 3] + b2[bh];
    sc = sc > 0.f ? sc : NEG_SLOPE * sc;
    if (e_w < ne) scores[(size_t)eids[e_w] * H + h] = sc;
}

// ---------------- softmax + V aggregation: 256 threads, wave = head ----------------
__global__ __launch_bounds__(256) void agg_kernel(
    const float* __restrict__ V, const float* __restrict__ scores,
    const int* __restrict__ rowStart, const int* __restrict__ edge_col,
    const int* __restrict__ edge_eid, float* __restrict__ out_attn)
{
    const int row = blockIdx.x;
    const int tid = threadIdx.x;
    const int lane = tid & 63;
    const int h = tid >> 6;
    const int beg = rowStart[row];
    int deg = rowStart[row + 1] - beg;
    if (deg > MAXDEG) deg = MAXDEG;

    __shared__ int tcol[MAXDEG], teid[MAXDEG];
    __shared__ int scol[MAXDEG], seid[MAXDEG];
    __shared__ int win[MAXDEG];
    __shared__ float wgt[4][MAXDEG];

    for (int a = tid; a < deg; a += 256) { tcol[a] = edge_col[beg + a]; teid[a] = edge_eid[beg + a]; }
    __syncthreads();
    // deterministic sort by (unique) global edge id via rank
    for (int a = tid; a < deg; a += 256) {
        const int e = teid[a];
        int r = 0;
        for (int b = 0; b < deg; ++b) r += (teid[b] < e);
        scol[r] = tcol[a];
        seid[r] = e;
    }
    __syncthreads();
    // winner = last occurrence of each column in edge-index order
    for (int a = tid; a < deg; a += 256) {
        const int c = scol[a];
        int wn = 1;
        for (int b = a + 1; b < deg; ++b) if (scol[b] == c) { wn = 0; break; }
        win[a] = wn;
    }
    __syncthreads();

    float m = -1e30f;
    for (int a = lane; a < deg; a += 64)
        if (win[a]) m = fmaxf(m, scores[(size_t)seid[a] * H + h]);
#pragma unroll
    for (int off = 32; off; off >>= 1) m = fmaxf(m, __shfl_xor(m, off, 64));

    float dn = 0.f;
    for (int a = lane; a < deg; a += 64) {
        const float wv = win[a] ? __expf(scores[(size_t)seid[a] * H + h] - m) : 0.f;
        wgt[h][a] = wv;
        dn += wv;
    }
#pragma unroll
    for (int off = 32; off; off >>= 1) dn += __shfl_xor(dn, off, 64);

    float accv = 0.f;
    for (int a = 0; a < deg; ++a) {
        const float wv = wgt[h][a];
        if (wv != 0.f) accv += wv * V[(size_t)scol[a] * D + lane];
    }
    out_attn[(size_t)row * (H * D) + h * D + lane] = accv / dn;
}

// ---------------- final projection: [N,256] @ [256,64] + Pb ----------------
__global__ void proj_kernel(const float* __restrict__ out_attn, const float* __restrict__ Pw,
                            const float* __restrict__ Pb, float* __restrict__ out)
{
    __shared__ float r[H * D];
    const int n = blockIdx.x, d = threadIdx.x;  // 64 threads
    for (int i = d; i < H * D; i += D) r[i] = out_attn[(size_t)n * (H * D) + i];
    __syncthreads();
    float acc = Pb[d];
#pragma unroll 8
    for (int k = 0; k < H * D; ++k) acc += r[k] * Pw[k * D + d];
    out[(size_t)n * D + d] = acc;
}

extern "C" void kernel_launch(void* const* d_in, const int* in_sizes, int n_in,
                              void* d_out, int out_size, void* d_ws, size_t ws_size,
                              hipStream_t stream)
{
    const float* emb = (const float*)d_in[0];
    const float* Qw  = (const float*)d_in[1];
    const float* Qb  = (const float*)d_in[2];
    const float* Kw  = (const float*)d_in[3];
    const float* Kb  = (const float*)d_in[4];
    const float* Vw  = (const float*)d_in[5];
    const float* Vb  = (const float*)d_in[6];
    const float* W0  = (const float*)d_in[7];
    const float* b0  = (const float*)d_in[8];
    const float* W1  = (const float*)d_in[9];
    const float* b1  = (const float*)d_in[10];
    const float* W2  = (const float*)d_in[11];
    const float* b2  = (const float*)d_in[12];
    const float* Pw  = (const float*)d_in[13];
    const float* Pb  = (const float*)d_in[14];
    const int* src   = (const int*)d_in[15];
    const int* dst   = (const int*)d_in[16];
    const int* bond  = (const int*)d_in[17];

    const int N  = in_sizes[0] / D;
    const int Ep = in_sizes[15];
    const int TE = 2 * Ep;
    const int nblk = (TE + 255) / 256;
    const int nq = (N + 3) / 4;

    // ---- workspace layout ----
    char* w = (char*)d_ws;
    auto alloc = [&](size_t bytes) -> void* {
        void* p = (void*)w;
        w += ((bytes + 255) / 256) * 256;
        return p;
    };
    unsigned short* Qbf = (unsigned short*)alloc((size_t)N * D * 2);
    unsigned short* Kbf = (unsigned short*)alloc((size_t)N * D * 2);
    float* V        = (float*)alloc((size_t)N * D * 4);
    unsigned short* W0p = (unsigned short*)alloc((size_t)131072 * 2);
    unsigned short* W1p = (unsigned short*)alloc((size_t)65536 * 2);
    float* scores   = (float*)alloc((size_t)TE * H * 4);
    float* out_attn = (float*)alloc((size_t)N * H * D * 4);
    int* rowStart   = (int*)alloc((size_t)(N + 1) * 4);
    int* bondOff    = (int*)alloc((size_t)(NB + 1) * 4);
    int* edge_col   = (int*)alloc((size_t)TE * 4);
    int* edge_eid   = (int*)alloc((size_t)TE * 4);
    int* bond_edges = (int*)alloc((size_t)TE * 4);
    int* blockBondCnt  = (int*)alloc((size_t)NB * nblk * 4);
    int* blockBondBase = (int*)alloc((size_t)NB * nblk * 4);
    int* counters   = (int*)alloc((size_t)(2 * N) * 4);
    if ((size_t)(w - (char*)d_ws) > ws_size) return;

    int* rowCnt  = counters;
    int* rowFill = counters + N;

    prep_kernel<<<nq + 512, 256, 0, stream>>>(emb, Qw, Qb, Kw, Kb, Vw, Vb, Qbf, Kbf, V,
                                              W0, W1, W0p, W1p, counters, N, nq);
    count_kernel<<<nblk, 256, 0, stream>>>(src, dst, bond, Ep, rowCnt, blockBondCnt, nblk);
    scan_kernel<<<1, 1024, 0, stream>>>(rowCnt, rowStart, blockBondCnt, blockBondBase,
                                        bondOff, N, nblk);
    scatter_kernel<<<nblk, 256, 0, stream>>>(src, dst, bond, Ep, rowStart, rowFill,
                                             blockBondBase, nblk, edge_col, edge_eid,
                                             bond_edges);
    dim3 mgrid((TE + TILE - 1) / TILE, NB);
    mlp_kernel<<<mgrid, 256, 0, stream>>>(Qbf, Kbf, src, dst, Ep, bondOff, bond_edges,
                                          W0p, W1p, b0, b1, W2, b2, scores);
    agg_kernel<<<N, 256, 0, stream>>>(V, scores, rowStart, edge_col, edge_eid, out_attn);
    proj_kernel<<<N, D, 0, stream>>>(out_attn, Pw, Pb, (float*)d_out);
}